// Round 2
// baseline (414763.037 us; speedup 1.0000x reference)
//
#include <hip/hip_runtime.h>

#define HSZ 1024
#define TSTEPS 4096
#define NBLK 256
#define NTHR 256  // 4 waves/block -> 1024 waves total == HSZ

__device__ __forceinline__ float wave_reduce(float v) {
#pragma unroll
    for (int off = 32; off; off >>= 1) v += __shfl_xor(v, off, 64);
    return v;
}

__device__ __forceinline__ float sigm(float x) { return 1.0f / (1.0f + __expf(-x)); }

__device__ __forceinline__ float dot4(const float4 a, const float4 b) {
    return a.x * b.x + a.y * b.y + a.z * b.z + a.w * b.w;
}

// Device-wide barrier without cooperative launch.
// flags: int[NBLK] in d_ws, poisoned 0xAAAAAAAA (negative) before each launch,
// so "flags[j] < epoch" (epoch >= 1) spins correctly with no init race.
// Epochs grow monotonically within one launch; harness re-poison resets state.
__device__ __forceinline__ void gbar(int* flags, int epoch) {
    __syncthreads();       // all block threads done; their stores drained to L2
    __threadfence();       // agent-scope release: publish device-wide
    if (threadIdx.x == 0)
        __hip_atomic_store(flags + blockIdx.x, epoch, __ATOMIC_RELAXED,
                           __HIP_MEMORY_SCOPE_AGENT);
    // NTHR == NBLK: thread j polls block j's flag
    while (__hip_atomic_load(flags + threadIdx.x, __ATOMIC_RELAXED,
                             __HIP_MEMORY_SCOPE_AGENT) < epoch) {}
    __syncthreads();
    __threadfence();       // agent-scope acquire: invalidate stale cache lines
}

__global__ void __launch_bounds__(NTHR) lstm_persist(
    const float* __restrict__ x,
    const float* __restrict__ Wih0, const float* __restrict__ Whh0,
    const float* __restrict__ bih0, const float* __restrict__ bhh0,
    const float* __restrict__ Wih12, const float* __restrict__ Whh12,
    const float* __restrict__ bih12, const float* __restrict__ bhh12,
    const float* __restrict__ Wres, const float* __restrict__ bres,
    float* __restrict__ out, float* __restrict__ ws)
{
    const int lane = threadIdx.x & 63;
    const int gw = blockIdx.x * (NTHR / 64) + (threadIdx.x >> 6);  // 0..1023
    const int w = gw;  // hidden unit owned by this wave

    // ws layout: h buffers [2 parity][3 layers][HSZ] floats, then int flags[NBLK]
    int* flags = (int*)(ws + 2 * 3 * HSZ);

    // zero-init h buffers (ws is poisoned before every launch)
    for (int i = blockIdx.x * NTHR + threadIdx.x; i < 2 * 3 * HSZ; i += NBLK * NTHR)
        ws[i] = 0.0f;

    // Preload per-wave constants: combined biases + layer0 input weights (2 cols)
    float b0[4], b1[4], b2[4], wx0a[4], wx0b[4];
#pragma unroll
    for (int g = 0; g < 4; ++g) {
        const int r = g * HSZ + w;
        b0[g] = bih0[r] + bhh0[r];
        b1[g] = bih12[r] + bhh12[r];
        b2[g] = bih12[4 * HSZ + r] + bhh12[4 * HSZ + r];
        wx0a[g] = Wih0[2 * r];
        wx0b[g] = Wih0[2 * r + 1];
    }
    float c0 = 0.0f, c1 = 0.0f, c2 = 0.0f;

    const int HV = HSZ / 4;  // float4 per row
    const float4* Whh0v = (const float4*)Whh0;
    const float4* Wih1v = (const float4*)Wih12;
    const float4* Whh1v = (const float4*)Whh12;
    const float4* Wih2v = (const float4*)(Wih12 + 4 * HSZ * HSZ);
    const float4* Whh2v = (const float4*)(Whh12 + 4 * HSZ * HSZ);

    int ep = 1;
    gbar(flags, ep++);  // init visible everywhere

    for (int t = 0; t < TSTEPS; ++t) {
        const int rp = t & 1, wp = rp ^ 1;
        const float* h0r = ws + (rp * 3 + 0) * HSZ;
        const float* h1r = ws + (rp * 3 + 1) * HSZ;
        const float* h2r = ws + (rp * 3 + 2) * HSZ;
        float* h0w = ws + (wp * 3 + 0) * HSZ;
        float* h1w = ws + (wp * 3 + 1) * HSZ;
        float* h2w = ws + (wp * 3 + 2) * HSZ;

        // ---------------- stage 0: layer 0 ----------------
        {
            float4 hreg[4];
            const float4* h4 = (const float4*)h0r;
#pragma unroll
            for (int i = 0; i < 4; ++i) hreg[i] = h4[lane + 64 * i];
            const float x0 = x[2 * t], x1 = x[2 * t + 1];
            float gacc[4];
#pragma unroll
            for (int g = 0; g < 4; ++g) {
                const float4* row = Whh0v + (size_t)(g * HSZ + w) * HV;
                float a = 0.0f;
#pragma unroll
                for (int i = 0; i < 4; ++i) a += dot4(row[lane + 64 * i], hreg[i]);
                gacc[g] = a;
            }
#pragma unroll
            for (int g = 0; g < 4; ++g)
                gacc[g] = wave_reduce(gacc[g]) + b0[g] + wx0a[g] * x0 + wx0b[g] * x1;
            const float ig = sigm(gacc[0]), fg = sigm(gacc[1]);
            const float gg = tanhf(gacc[2]), og = sigm(gacc[3]);
            c0 = fg * c0 + ig * gg;
            const float hn = og * tanhf(c0);
            if (lane == 0) h0w[w] = hn;

            // output head for t-1 (h2(t-1) lives in buffer rp, stable this step)
            if (gw == 0 && t > 0) {
                const float4* h2p = (const float4*)h2r;
                const float4* wr = (const float4*)Wres;
                float a = 0.0f;
#pragma unroll
                for (int i = 0; i < 4; ++i) a += dot4(wr[lane + 64 * i], h2p[lane + 64 * i]);
                a = wave_reduce(a) + bres[0];
                if (lane == 0) out[t - 1] = sigm(a);
            }
        }
        gbar(flags, ep++);

        // ---------------- stage 1: layer 1 ----------------
        {
            float4 ha[4], hb[4];
            const float4* h4a = (const float4*)h0w;  // new h0
            const float4* h4b = (const float4*)h1r;  // old h1
#pragma unroll
            for (int i = 0; i < 4; ++i) { ha[i] = h4a[lane + 64 * i]; hb[i] = h4b[lane + 64 * i]; }
            float gacc[4];
#pragma unroll
            for (int g = 0; g < 4; ++g) {
                const float4* rowi = Wih1v + (size_t)(g * HSZ + w) * HV;
                const float4* rowh = Whh1v + (size_t)(g * HSZ + w) * HV;
                float a = 0.0f;
#pragma unroll
                for (int i = 0; i < 4; ++i) {
                    a += dot4(rowi[lane + 64 * i], ha[i]);
                    a += dot4(rowh[lane + 64 * i], hb[i]);
                }
                gacc[g] = a;
            }
#pragma unroll
            for (int g = 0; g < 4; ++g) gacc[g] = wave_reduce(gacc[g]) + b1[g];
            const float ig = sigm(gacc[0]), fg = sigm(gacc[1]);
            const float gg = tanhf(gacc[2]), og = sigm(gacc[3]);
            c1 = fg * c1 + ig * gg;
            const float hn = og * tanhf(c1);
            if (lane == 0) h1w[w] = hn;
        }
        gbar(flags, ep++);

        // ---------------- stage 2: layer 2 ----------------
        {
            float4 ha[4], hb[4];
            const float4* h4a = (const float4*)h1w;  // new h1
            const float4* h4b = (const float4*)h2r;  // old h2
#pragma unroll
            for (int i = 0; i < 4; ++i) { ha[i] = h4a[lane + 64 * i]; hb[i] = h4b[lane + 64 * i]; }
            float gacc[4];
#pragma unroll
            for (int g = 0; g < 4; ++g) {
                const float4* rowi = Wih2v + (size_t)(g * HSZ + w) * HV;
                const float4* rowh = Whh2v + (size_t)(g * HSZ + w) * HV;
                float a = 0.0f;
#pragma unroll
                for (int i = 0; i < 4; ++i) {
                    a += dot4(rowi[lane + 64 * i], ha[i]);
                    a += dot4(rowh[lane + 64 * i], hb[i]);
                }
                gacc[g] = a;
            }
#pragma unroll
            for (int g = 0; g < 4; ++g) gacc[g] = wave_reduce(gacc[g]) + b2[g];
            const float ig = sigm(gacc[0]), fg = sigm(gacc[1]);
            const float gg = tanhf(gacc[2]), og = sigm(gacc[3]);
            c2 = fg * c2 + ig * gg;
            const float hn = og * tanhf(c2);
            if (lane == 0) h2w[w] = hn;
        }
        gbar(flags, ep++);
    }

    // final output y[T-1]: h2(T-1) is in buffer parity (T & 1) == 0
    if (gw == 0) {
        const float4* h2p = (const float4*)(ws + ((TSTEPS & 1) * 3 + 2) * HSZ);
        const float4* wr = (const float4*)Wres;
        float a = 0.0f;
#pragma unroll
        for (int i = 0; i < 4; ++i) a += dot4(wr[lane + 64 * i], h2p[lane + 64 * i]);
        a = wave_reduce(a) + bres[0];
        if (lane == 0) out[TSTEPS - 1] = sigm(a);
    }
}

extern "C" void kernel_launch(void* const* d_in, const int* in_sizes, int n_in,
                              void* d_out, int out_size, void* d_ws, size_t ws_size,
                              hipStream_t stream) {
    const float* x     = (const float*)d_in[0];
    const float* Wih0  = (const float*)d_in[1];
    const float* Whh0  = (const float*)d_in[2];
    const float* bih0  = (const float*)d_in[3];
    const float* bhh0  = (const float*)d_in[4];
    const float* Wih12 = (const float*)d_in[5];
    const float* Whh12 = (const float*)d_in[6];
    const float* bih12 = (const float*)d_in[7];
    const float* bhh12 = (const float*)d_in[8];
    const float* Wres  = (const float*)d_in[9];
    const float* bres  = (const float*)d_in[10];
    float* out = (float*)d_out;
    float* ws  = (float*)d_ws;

    lstm_persist<<<dim3(NBLK), dim3(NTHR), 0, stream>>>(
        x, Wih0, Whh0, bih0, bhh0, Wih12, Whh12, bih12, bhh12,
        Wres, bres, out, ws);
}

// Round 3
// 148217.065 us; speedup vs baseline: 2.7983x; 2.7983x over previous
//
#include <hip/hip_runtime.h>

#define HSZ 1024
#define TSTEPS 4096
#define NBLK 256
#define NTHR 256   // 4 waves/block x 256 blocks = 1024 waves == HSZ units
#define HV (HSZ / 4)

__device__ __forceinline__ float wave_reduce(float v) {
#pragma unroll
    for (int off = 32; off; off >>= 1) v += __shfl_xor(v, off, 64);
    return v;
}

__device__ __forceinline__ float sigm(float x) { return 1.0f / (1.0f + __expf(-x)); }

__device__ __forceinline__ float dot4(const float4 a, const float4 b) {
    return a.x * b.x + a.y * b.y + a.z * b.z + a.w * b.w;
}

// Device-wide barrier, storm-free version:
// - flags[NBLK] in d_ws, poisoned negative before each launch, epochs >= 1.
// - only wave 0 polls; 64 lanes cover 256 flags (4 each), __all() vote,
//   s_sleep backoff. Other waves park at __syncthreads.
__device__ __forceinline__ void gbar(int* flags, int epoch) {
    __syncthreads();
    __threadfence();  // release: publish h stores device-wide
    if (threadIdx.x == 0)
        __hip_atomic_store(flags + blockIdx.x, epoch, __ATOMIC_RELAXED,
                           __HIP_MEMORY_SCOPE_AGENT);
    if (threadIdx.x < 64) {
        for (;;) {
            int ok = 1;
#pragma unroll
            for (int j = 0; j < 4; ++j)
                ok &= (__hip_atomic_load(flags + threadIdx.x + 64 * j,
                                         __ATOMIC_RELAXED,
                                         __HIP_MEMORY_SCOPE_AGENT) >= epoch);
            if (__all(ok)) break;
            __builtin_amdgcn_s_sleep(2);
        }
    }
    __syncthreads();
    __threadfence();  // acquire: subsequent h loads see fresh data
}

// __launch_bounds__(256, 1): 1 wave/SIMD -> up to 512 VGPRs, no spill for
// the ~400 we need (320 of them are the register-resident weights).
__global__ void __launch_bounds__(NTHR, 1) lstm_persist(
    const float* __restrict__ x,
    const float* __restrict__ Wih0, const float* __restrict__ Whh0,
    const float* __restrict__ bih0, const float* __restrict__ bhh0,
    const float* __restrict__ Wih12, const float* __restrict__ Whh12,
    const float* __restrict__ bih12, const float* __restrict__ bhh12,
    const float* __restrict__ Wres, const float* __restrict__ bres,
    float* __restrict__ out, float* __restrict__ ws)
{
    const int lane = threadIdx.x & 63;
    const int u = blockIdx.x * (NTHR / 64) + (threadIdx.x >> 6);  // hidden unit 0..1023

    // ws layout: h buffers [2 parity][3 layers][HSZ] floats, then int flags[NBLK]
    int* flags = (int*)(ws + 6 * HSZ);

    // zero-init both parities of h buffers (ws is poisoned before every launch)
    for (int i = blockIdx.x * NTHR + threadIdx.x; i < 6 * HSZ; i += NBLK * NTHR)
        ws[i] = 0.0f;

    // ---- per-wave constants: combined biases + layer0 input weights ----
    float b0[4], b1[4], b2[4], wx0a[4], wx0b[4];
#pragma unroll
    for (int g = 0; g < 4; ++g) {
        const int r = g * HSZ + u;
        b0[g] = bih0[r] + bhh0[r];
        b1[g] = bih12[r] + bhh12[r];
        b2[g] = bih12[4 * HSZ + r] + bhh12[4 * HSZ + r];
        wx0a[g] = Wih0[2 * r];
        wx0b[g] = Wih0[2 * r + 1];
    }

    // ---- register-resident weights: 20 rows x 1024 fp32 = 80 float4/lane ----
    const float4* Whh0v = (const float4*)Whh0;
    const float4* Wih1v = (const float4*)Wih12;
    const float4* Whh1v = (const float4*)Whh12;
    const float4* Wih2v = (const float4*)(Wih12 + 4 * HSZ * HSZ);
    const float4* Whh2v = (const float4*)(Whh12 + 4 * HSZ * HSZ);

    float4 w0[4][4], wi1[4][4], wh1[4][4], wi2[4][4], wh2[4][4];
#pragma unroll
    for (int g = 0; g < 4; ++g) {
        const size_t r = (size_t)(g * HSZ + u) * HV + lane;
#pragma unroll
        for (int i = 0; i < 4; ++i) {
            w0[g][i]  = Whh0v[r + 64 * i];
            wi1[g][i] = Wih1v[r + 64 * i];
            wh1[g][i] = Whh1v[r + 64 * i];
            wi2[g][i] = Wih2v[r + 64 * i];
            wh2[g][i] = Whh2v[r + 64 * i];
        }
    }

    float c0 = 0.0f, c1 = 0.0f, c2 = 0.0f;
    int ep = 1;
    gbar(flags, ep++);  // init + weight loads visible/complete

    // Wavefront pipeline: iter k computes layer0(t=k), layer1(t=k-1),
    // layer2(t=k-2), head y(k-3). All reads come from parity rp (written at
    // iter k-1); all writes go to parity wp. ONE barrier per iteration.
    for (int k = 0; k <= TSTEPS + 1; ++k) {
        const int wp = k & 1, rp = wp ^ 1;
        const float4* h0r = (const float4*)(ws + (rp * 3 + 0) * HSZ);
        const float4* h1r = (const float4*)(ws + (rp * 3 + 1) * HSZ);
        const float4* h2r = (const float4*)(ws + (rp * 3 + 2) * HSZ);
        float* h0w = ws + (wp * 3 + 0) * HSZ;
        float* h1w = ws + (wp * 3 + 1) * HSZ;
        float* h2w = ws + (wp * 3 + 2) * HSZ;

        // shared h-vector fragments (each used by two adjacent layers)
        float4 ha[4], hb[4], hc[4];
#pragma unroll
        for (int i = 0; i < 4; ++i) {
            ha[i] = h0r[lane + 64 * i];   // h0(k-1)
            hb[i] = h1r[lane + 64 * i];   // h1(k-2)
            hc[i] = h2r[lane + 64 * i];   // h2(k-3)
        }

        // ---- head: y(k-3) = sigm(Wres . h2(k-3) + b) ----
        if (u == 0 && k >= 3) {
            const float4* wr = (const float4*)Wres;
            float a = 0.0f;
#pragma unroll
            for (int i = 0; i < 4; ++i) a += dot4(wr[lane + 64 * i], hc[i]);
            a = wave_reduce(a) + bres[0];
            if (lane == 0) out[k - 3] = sigm(a);
        }

        // ---- layer 0, t = k ----
        if (k < TSTEPS) {
            const float x0 = x[2 * k], x1 = x[2 * k + 1];
            float acc[4];
#pragma unroll
            for (int g = 0; g < 4; ++g) {
                float a = 0.0f;
#pragma unroll
                for (int i = 0; i < 4; ++i) a += dot4(w0[g][i], ha[i]);
                acc[g] = a;
            }
#pragma unroll
            for (int g = 0; g < 4; ++g)
                acc[g] = wave_reduce(acc[g]) + b0[g] + wx0a[g] * x0 + wx0b[g] * x1;
            const float ig = sigm(acc[0]), fg = sigm(acc[1]);
            const float gg = tanhf(acc[2]), og = sigm(acc[3]);
            c0 = fg * c0 + ig * gg;
            if (lane == 0) h0w[u] = og * tanhf(c0);
        }

        // ---- layer 1, t = k-1: Wih1.h0(k-1) + Whh1.h1(k-2) ----
        if (k >= 1 && k <= TSTEPS) {
            float acc[4];
#pragma unroll
            for (int g = 0; g < 4; ++g) {
                float a = 0.0f;
#pragma unroll
                for (int i = 0; i < 4; ++i) {
                    a += dot4(wi1[g][i], ha[i]);
                    a += dot4(wh1[g][i], hb[i]);
                }
                acc[g] = a;
            }
#pragma unroll
            for (int g = 0; g < 4; ++g) acc[g] = wave_reduce(acc[g]) + b1[g];
            const float ig = sigm(acc[0]), fg = sigm(acc[1]);
            const float gg = tanhf(acc[2]), og = sigm(acc[3]);
            c1 = fg * c1 + ig * gg;
            if (lane == 0) h1w[u] = og * tanhf(c1);
        }

        // ---- layer 2, t = k-2: Wih2.h1(k-2) + Whh2.h2(k-3) ----
        if (k >= 2) {
            float acc[4];
#pragma unroll
            for (int g = 0; g < 4; ++g) {
                float a = 0.0f;
#pragma unroll
                for (int i = 0; i < 4; ++i) {
                    a += dot4(wi2[g][i], hb[i]);
                    a += dot4(wh2[g][i], hc[i]);
                }
                acc[g] = a;
            }
#pragma unroll
            for (int g = 0; g < 4; ++g) acc[g] = wave_reduce(acc[g]) + b2[g];
            const float ig = sigm(acc[0]), fg = sigm(acc[1]);
            const float gg = tanhf(acc[2]), og = sigm(acc[3]);
            c2 = fg * c2 + ig * gg;
            if (lane == 0) h2w[u] = og * tanhf(c2);
        }

        gbar(flags, ep++);
    }

    // final output y(T-1): h2(T-1) written at iter T+1 to parity (T+1)&1;
    // last loop barrier already made it visible.
    if (u == 0) {
        const float4* h2p =
            (const float4*)(ws + (((TSTEPS + 1) & 1) * 3 + 2) * HSZ);
        const float4* wr = (const float4*)Wres;
        float a = 0.0f;
#pragma unroll
        for (int i = 0; i < 4; ++i)
            a += dot4(wr[lane + 64 * i], h2p[lane + 64 * i]);
        a = wave_reduce(a) + bres[0];
        if (lane == 0) out[TSTEPS - 1] = sigm(a);
    }
}

extern "C" void kernel_launch(void* const* d_in, const int* in_sizes, int n_in,
                              void* d_out, int out_size, void* d_ws, size_t ws_size,
                              hipStream_t stream) {
    const float* x     = (const float*)d_in[0];
    const float* Wih0  = (const float*)d_in[1];
    const float* Whh0  = (const float*)d_in[2];
    const float* bih0  = (const float*)d_in[3];
    const float* bhh0  = (const float*)d_in[4];
    const float* Wih12 = (const float*)d_in[5];
    const float* Whh12 = (const float*)d_in[6];
    const float* bih12 = (const float*)d_in[7];
    const float* bhh12 = (const float*)d_in[8];
    const float* Wres  = (const float*)d_in[9];
    const float* bres  = (const float*)d_in[10];
    float* out = (float*)d_out;
    float* ws  = (float*)d_ws;

    lstm_persist<<<dim3(NBLK), dim3(NTHR), 0, stream>>>(
        x, Wih0, Whh0, bih0, bhh0, Wih12, Whh12, bih12, bhh12,
        Wres, bres, out, ws);
}

// Round 4
// 36493.735 us; speedup vs baseline: 11.3653x; 4.0614x over previous
//
#include <hip/hip_runtime.h>

#define HSZ 1024
#define TSTEPS 4096
#define NBLK 256
#define NTHR 256   // 4 waves/block x 256 blocks = 1024 waves == HSZ units
#define HV (HSZ / 4)

__device__ __forceinline__ float wave_reduce(float v) {
#pragma unroll
    for (int off = 32; off; off >>= 1) v += __shfl_xor(v, off, 64);
    return v;
}

__device__ __forceinline__ float sigm(float x) { return 1.0f / (1.0f + __expf(-x)); }

__device__ __forceinline__ float dot4(const float4 a, const float4 b) {
    return a.x * b.x + a.y * b.y + a.z * b.z + a.w * b.w;
}

// ---- agent-coherent (L3-level) accesses: sc1 path, NO cache fences ----
__device__ __forceinline__ void st_coh(float* p, float v) {
    __hip_atomic_store(p, v, __ATOMIC_RELAXED, __HIP_MEMORY_SCOPE_AGENT);
}
__device__ __forceinline__ float2 ld_coh8(const void* p) {
    unsigned long long raw = __hip_atomic_load(
        (const unsigned long long*)p, __ATOMIC_RELAXED, __HIP_MEMORY_SCOPE_AGENT);
    union { unsigned long long u; float2 f; } cv; cv.u = raw;
    return cv.f;
}

// Pin a value into a VGPR so the compiler cannot re-sink its defining load
// into the loop (forces true register residency of the weights).
#define PIN(f) asm volatile("" : "+v"(f))
#define PIN4(q) do { PIN((q).x); PIN((q).y); PIN((q).z); PIN((q).w); } while (0)

// Device barrier with NO cache-invalidating fences:
// all shared data travels via sc1 (coherence-point) accesses, so ordering
// only needs: own vmem drained (s_waitcnt vmcnt 0) -> block drained
// (__syncthreads) -> flag store (agent relaxed) -> wave0 polls all flags.
__device__ __forceinline__ void gbar(int* flags, int epoch) {
    asm volatile("s_waitcnt vmcnt(0)" ::: "memory");
    __syncthreads();
    if (threadIdx.x == 0)
        __hip_atomic_store(flags + blockIdx.x, epoch, __ATOMIC_RELAXED,
                           __HIP_MEMORY_SCOPE_AGENT);
    if (threadIdx.x < 64) {
        for (;;) {
            int ok = 1;
#pragma unroll
            for (int j = 0; j < 4; ++j)
                ok &= (__hip_atomic_load(flags + (threadIdx.x & 63) + 64 * j,
                                         __ATOMIC_RELAXED,
                                         __HIP_MEMORY_SCOPE_AGENT) >= epoch);
            if (__all(ok)) break;
            __builtin_amdgcn_s_sleep(1);
        }
    }
    __syncthreads();
}

__global__ void __launch_bounds__(NTHR, 1) lstm_persist(
    const float* __restrict__ x,
    const float* __restrict__ Wih0, const float* __restrict__ Whh0,
    const float* __restrict__ bih0, const float* __restrict__ bhh0,
    const float* __restrict__ Wih12, const float* __restrict__ Whh12,
    const float* __restrict__ bih12, const float* __restrict__ bhh12,
    const float* __restrict__ Wres, const float* __restrict__ bres,
    float* __restrict__ out, float* __restrict__ ws)
{
    const int lane = threadIdx.x & 63;
    const int u = blockIdx.x * (NTHR / 64) + (threadIdx.x >> 6);  // hidden unit

    // ws: h buffers [2 parity][3 layers][HSZ] floats, then int flags[NBLK]
    int* flags = (int*)(ws + 6 * HSZ);
    __shared__ float hlds[3 * HSZ];  // staged h0/h1/h2 for this iteration

    // zero-init both parities via coherent stores (L3 holds zeros)
    for (int i = blockIdx.x * NTHR + threadIdx.x; i < 6 * HSZ; i += NBLK * NTHR)
        st_coh(ws + i, 0.0f);

    // ---- per-wave constants ----
    float b0[4], b1[4], b2[4], wx0a[4], wx0b[4];
#pragma unroll
    for (int g = 0; g < 4; ++g) {
        const int r = g * HSZ + u;
        b0[g] = bih0[r] + bhh0[r];
        b1[g] = bih12[r] + bhh12[r];
        b2[g] = bih12[4 * HSZ + r] + bhh12[4 * HSZ + r];
        wx0a[g] = Wih0[2 * r];
        wx0b[g] = Wih0[2 * r + 1];
    }

    // ---- register-resident weights: 20 rows x 1024 fp32 = 320 VGPRs/lane ----
    const float4* Whh0v = (const float4*)Whh0;
    const float4* Wih1v = (const float4*)Wih12;
    const float4* Whh1v = (const float4*)Whh12;
    const float4* Wih2v = (const float4*)(Wih12 + 4 * HSZ * HSZ);
    const float4* Whh2v = (const float4*)(Whh12 + 4 * HSZ * HSZ);

    float4 w0[4][4], wi1[4][4], wh1[4][4], wi2[4][4], wh2[4][4];
#pragma unroll
    for (int g = 0; g < 4; ++g) {
        const size_t r = (size_t)(g * HSZ + u) * HV + lane;
#pragma unroll
        for (int i = 0; i < 4; ++i) {
            w0[g][i]  = Whh0v[r + 64 * i];
            wi1[g][i] = Wih1v[r + 64 * i];
            wh1[g][i] = Whh1v[r + 64 * i];
            wi2[g][i] = Wih2v[r + 64 * i];
            wh2[g][i] = Whh2v[r + 64 * i];
        }
    }
#pragma unroll
    for (int g = 0; g < 4; ++g)
#pragma unroll
        for (int i = 0; i < 4; ++i) {
            PIN4(w0[g][i]); PIN4(wi1[g][i]); PIN4(wh1[g][i]);
            PIN4(wi2[g][i]); PIN4(wh2[g][i]);
        }

    // head weights (only wave u==0 uses them)
    float4 wres[4];
    if (u == 0) {
#pragma unroll
        for (int i = 0; i < 4; ++i) wres[i] = ((const float4*)Wres)[lane + 64 * i];
    }
    const float bres0 = bres[0];

    float c0 = 0.0f, c1 = 0.0f, c2 = 0.0f;
    int ep = 1;
    gbar(flags, ep++);  // zero-init visible at L3 everywhere

    // Wavefront pipeline: iter k computes layer0(t=k), layer1(k-1),
    // layer2(k-2), head y(k-3). Reads = parity rp (stores of iter k-1),
    // writes = parity wp. ONE barrier per iteration.
    for (int k = 0; k <= TSTEPS + 2; ++k) {
        const int wp = k & 1, rp = wp ^ 1;

        // ---- cooperative coherent load of h(rp) -> LDS (12 KB/block) ----
        {
            const char* src = (const char*)(ws + rp * 3 * HSZ);
            float2* dst = (float2*)hlds;
#pragma unroll
            for (int j = 0; j < 6; ++j) {
                const int idx = j * NTHR + threadIdx.x;  // 1536 float2 total
                dst[idx] = ld_coh8(src + idx * 8);
            }
        }
        __syncthreads();

        float4 ha[4], hb[4], hc[4];
        {
            const float4* h4 = (const float4*)hlds;
#pragma unroll
            for (int i = 0; i < 4; ++i) {
                ha[i] = h4[lane + 64 * i];          // h0(k-1)
                hb[i] = h4[256 + lane + 64 * i];    // h1(k-2)
                hc[i] = h4[512 + lane + 64 * i];    // h2(k-3)
            }
        }

        float* h0w = ws + (wp * 3 + 0) * HSZ;
        float* h1w = ws + (wp * 3 + 1) * HSZ;
        float* h2w = ws + (wp * 3 + 2) * HSZ;

        // ---- head: y(k-3) ----
        if (u == 0 && k >= 3) {
            float a = 0.0f;
#pragma unroll
            for (int i = 0; i < 4; ++i) a += dot4(wres[i], hc[i]);
            a = wave_reduce(a) + bres0;
            if (lane == 0) out[k - 3] = sigm(a);
        }

        // ---- layer 0, t = k ----
        if (k < TSTEPS) {
            const float x0 = x[2 * k], x1 = x[2 * k + 1];
            float acc[4];
#pragma unroll
            for (int g = 0; g < 4; ++g) {
                float a = 0.0f;
#pragma unroll
                for (int i = 0; i < 4; ++i) a += dot4(w0[g][i], ha[i]);
                acc[g] = a;
            }
#pragma unroll
            for (int g = 0; g < 4; ++g)
                acc[g] = wave_reduce(acc[g]) + b0[g] + wx0a[g] * x0 + wx0b[g] * x1;
            const float ig = sigm(acc[0]), fg = sigm(acc[1]);
            const float gg = tanhf(acc[2]), og = sigm(acc[3]);
            c0 = fg * c0 + ig * gg;
            if (lane == 0) st_coh(h0w + u, og * tanhf(c0));
        }

        // ---- layer 1, t = k-1 ----
        if (k >= 1 && k <= TSTEPS) {
            float acc[4];
#pragma unroll
            for (int g = 0; g < 4; ++g) {
                float a = 0.0f;
#pragma unroll
                for (int i = 0; i < 4; ++i) {
                    a += dot4(wi1[g][i], ha[i]);
                    a += dot4(wh1[g][i], hb[i]);
                }
                acc[g] = a;
            }
#pragma unroll
            for (int g = 0; g < 4; ++g) acc[g] = wave_reduce(acc[g]) + b1[g];
            const float ig = sigm(acc[0]), fg = sigm(acc[1]);
            const float gg = tanhf(acc[2]), og = sigm(acc[3]);
            c1 = fg * c1 + ig * gg;
            if (lane == 0) st_coh(h1w + u, og * tanhf(c1));
        }

        // ---- layer 2, t = k-2 ----
        if (k >= 2 && k <= TSTEPS + 1) {
            float acc[4];
#pragma unroll
            for (int g = 0; g < 4; ++g) {
                float a = 0.0f;
#pragma unroll
                for (int i = 0; i < 4; ++i) {
                    a += dot4(wi2[g][i], hb[i]);
                    a += dot4(wh2[g][i], hc[i]);
                }
                acc[g] = a;
            }
#pragma unroll
            for (int g = 0; g < 4; ++g) acc[g] = wave_reduce(acc[g]) + b2[g];
            const float ig = sigm(acc[0]), fg = sigm(acc[1]);
            const float gg = tanhf(acc[2]), og = sigm(acc[3]);
            c2 = fg * c2 + ig * gg;
            if (lane == 0) st_coh(h2w + u, og * tanhf(c2));
        }

        if (k < TSTEPS + 2) gbar(flags, ep++);  // last iter needs no publish
    }
}

extern "C" void kernel_launch(void* const* d_in, const int* in_sizes, int n_in,
                              void* d_out, int out_size, void* d_ws, size_t ws_size,
                              hipStream_t stream) {
    const float* x     = (const float*)d_in[0];
    const float* Wih0  = (const float*)d_in[1];
    const float* Whh0  = (const float*)d_in[2];
    const float* bih0  = (const float*)d_in[3];
    const float* bhh0  = (const float*)d_in[4];
    const float* Wih12 = (const float*)d_in[5];
    const float* Whh12 = (const float*)d_in[6];
    const float* bih12 = (const float*)d_in[7];
    const float* bhh12 = (const float*)d_in[8];
    const float* Wres  = (const float*)d_in[9];
    const float* bres  = (const float*)d_in[10];
    float* out = (float*)d_out;
    float* ws  = (float*)d_ws;

    lstm_persist<<<dim3(NBLK), dim3(NTHR), 0, stream>>>(
        x, Wih0, Whh0, bih0, bhh0, Wih12, Whh12, bih12, bhh12,
        Wres, bres, out, ws);
}

// Round 6
// 34223.495 us; speedup vs baseline: 12.1192x; 1.0663x over previous
//
#include <hip/hip_runtime.h>

#define HSZ 1024
#define TSTEPS 4096
#define NBLK 256
#define NTHR 256   // 4 waves/block x 256 blocks = 1024 waves == HSZ units
#define HV (HSZ / 4)

typedef _Float16 half2v __attribute__((ext_vector_type(2)));

#if __has_builtin(__builtin_amdgcn_fdot2)
#define FDOT2(a, b, c) __builtin_amdgcn_fdot2((a), (b), (c), false)
#else
__device__ __forceinline__ float FDOT2(half2v a, half2v b, float c) {
    return c + (float)a.x * (float)b.x + (float)a.y * (float)b.y;
}
#endif

__device__ __forceinline__ float wave_reduce(float v) {
#pragma unroll
    for (int off = 32; off; off >>= 1) v += __shfl_xor(v, off, 64);
    return v;
}

__device__ __forceinline__ float sigm(float x) { return 1.0f / (1.0f + __expf(-x)); }

// ---- agent-coherent (L3-level) accesses, no cache fences ----
__device__ __forceinline__ void st_coh(float* p, float v) {
    __hip_atomic_store(p, v, __ATOMIC_RELAXED, __HIP_MEMORY_SCOPE_AGENT);
}
__device__ __forceinline__ float2 ld_coh8(const void* p) {
    unsigned long long raw = __hip_atomic_load(
        (const unsigned long long*)p, __ATOMIC_RELAXED, __HIP_MEMORY_SCOPE_AGENT);
    union { unsigned long long u; float2 f; } cv; cv.u = raw;
    return cv.f;
}

// Pin packed-f16 weight into a VGPR (prevents load re-sinking).
#define PINH(h) asm volatile("" : "+v"(h))

// f32->half2 (init path, RNE per element)
__device__ __forceinline__ half2v cvt2(float a, float b) {
    half2v r; r.x = (_Float16)a; r.y = (_Float16)b; return r;
}

// f32x2 -> packed half2 via v_cvt_pkrtz; bit-cast __fp16x2 -> _Float16x2
// (identical 32-bit layout, memcpy folds to a register copy).
__device__ __forceinline__ half2v pkrtz(float a, float b) {
    auto t = __builtin_amdgcn_cvt_pkrtz(a, b);
    half2v r;
    __builtin_memcpy(&r, &t, sizeof(r));
    return r;
}

// Device barrier, no cache-scope fences (all shared data rides sc1 path).
__device__ __forceinline__ void gbar(int* flags, int epoch) {
    asm volatile("s_waitcnt vmcnt(0)" ::: "memory");
    __syncthreads();
    if (threadIdx.x == 0)
        __hip_atomic_store(flags + blockIdx.x, epoch, __ATOMIC_RELAXED,
                           __HIP_MEMORY_SCOPE_AGENT);
    if (threadIdx.x < 64) {
        for (;;) {
            int ok = 1;
#pragma unroll
            for (int j = 0; j < 4; ++j)
                ok &= (__hip_atomic_load(flags + (threadIdx.x & 63) + 64 * j,
                                         __ATOMIC_RELAXED,
                                         __HIP_MEMORY_SCOPE_AGENT) >= epoch);
            if (__all(ok)) break;
            __builtin_amdgcn_s_sleep(1);
        }
    }
    __syncthreads();
}

__global__ void __launch_bounds__(NTHR, 1) lstm_persist(
    const float* __restrict__ x,
    const float* __restrict__ Wih0, const float* __restrict__ Whh0,
    const float* __restrict__ bih0, const float* __restrict__ bhh0,
    const float* __restrict__ Wih12, const float* __restrict__ Whh12,
    const float* __restrict__ bih12, const float* __restrict__ bhh12,
    const float* __restrict__ Wres, const float* __restrict__ bres,
    float* __restrict__ out, float* __restrict__ ws)
{
    const int lane = threadIdx.x & 63;
    const int u = blockIdx.x * (NTHR / 64) + (threadIdx.x >> 6);  // hidden unit

    int* flags = (int*)(ws + 6 * HSZ);
    __shared__ float hlds[3 * HSZ];

    for (int i = blockIdx.x * NTHR + threadIdx.x; i < 6 * HSZ; i += NBLK * NTHR)
        st_coh(ws + i, 0.0f);

    // ---- per-wave scalar constants ----
    float b0[4], b1[4], b2[4], wx0a[4], wx0b[4];
#pragma unroll
    for (int g = 0; g < 4; ++g) {
        const int r = g * HSZ + u;
        b0[g] = bih0[r] + bhh0[r];
        b1[g] = bih12[r] + bhh12[r];
        b2[g] = bih12[4 * HSZ + r] + bhh12[4 * HSZ + r];
        wx0a[g] = Wih0[2 * r];
        wx0b[g] = Wih0[2 * r + 1];
    }

    // ---- register-resident f16 weights: 20 rows x 1024 -> 160 half2/lane ----
    const float4* Whh0v = (const float4*)Whh0;
    const float4* Wih1v = (const float4*)Wih12;
    const float4* Whh1v = (const float4*)Whh12;
    const float4* Wih2v = (const float4*)(Wih12 + 4 * HSZ * HSZ);
    const float4* Whh2v = (const float4*)(Whh12 + 4 * HSZ * HSZ);

    half2v w0h[4][8], wi1h[4][8], wh1h[4][8], wi2h[4][8], wh2h[4][8];
#pragma unroll
    for (int g = 0; g < 4; ++g) {
        const size_t r = (size_t)(g * HSZ + u) * HV + lane;
#pragma unroll
        for (int i = 0; i < 4; ++i) {
            float4 t;
            t = Whh0v[r + 64 * i];  w0h[g][2*i] = cvt2(t.x,t.y);  w0h[g][2*i+1] = cvt2(t.z,t.w);
            t = Wih1v[r + 64 * i];  wi1h[g][2*i] = cvt2(t.x,t.y); wi1h[g][2*i+1] = cvt2(t.z,t.w);
            t = Whh1v[r + 64 * i];  wh1h[g][2*i] = cvt2(t.x,t.y); wh1h[g][2*i+1] = cvt2(t.z,t.w);
            t = Wih2v[r + 64 * i];  wi2h[g][2*i] = cvt2(t.x,t.y); wi2h[g][2*i+1] = cvt2(t.z,t.w);
            t = Whh2v[r + 64 * i];  wh2h[g][2*i] = cvt2(t.x,t.y); wh2h[g][2*i+1] = cvt2(t.z,t.w);
        }
    }
#pragma unroll
    for (int g = 0; g < 4; ++g)
#pragma unroll
        for (int j = 0; j < 8; ++j) {
            PINH(w0h[g][j]); PINH(wi1h[g][j]); PINH(wh1h[g][j]);
            PINH(wi2h[g][j]); PINH(wh2h[g][j]);
        }

    // head weights as f16 (live only in wave u==0's path)
    half2v wresh[8];
    {
        const float4* wr = (const float4*)Wres;
#pragma unroll
        for (int i = 0; i < 4; ++i) {
            float4 t = wr[lane + 64 * i];
            wresh[2*i] = cvt2(t.x, t.y); wresh[2*i+1] = cvt2(t.z, t.w);
        }
    }
    const float bres0 = bres[0];

    float c0 = 0.0f, c1 = 0.0f, c2 = 0.0f;
    int ep = 1;
    gbar(flags, ep++);  // zero-init visible everywhere

    // Wavefront pipeline: iter k -> layer0(t=k), layer1(k-1), layer2(k-2),
    // head y(k-3). One barrier per iteration.
    for (int k = 0; k <= TSTEPS + 2; ++k) {
        const int wp = k & 1, rp = wp ^ 1;

        // cooperative coherent load of h(rp) -> LDS (12 KB/block)
        {
            const char* src = (const char*)(ws + rp * 3 * HSZ);
            float2* dst = (float2*)hlds;
#pragma unroll
            for (int j = 0; j < 6; ++j) {
                const int idx = j * NTHR + threadIdx.x;
                dst[idx] = ld_coh8(src + idx * 8);
            }
        }
        __syncthreads();

        // read fragments, convert to half2 (pkrtz) — one float4 live at a time
        half2v haf[8], hbf[8], hcf[8];
        {
            const float4* h4 = (const float4*)hlds;
#pragma unroll
            for (int i = 0; i < 4; ++i) {
                float4 t = h4[lane + 64 * i];                 // h0(k-1)
                haf[2*i]   = pkrtz(t.x, t.y);
                haf[2*i+1] = pkrtz(t.z, t.w);
                t = h4[256 + lane + 64 * i];                  // h1(k-2)
                hbf[2*i]   = pkrtz(t.x, t.y);
                hbf[2*i+1] = pkrtz(t.z, t.w);
                t = h4[512 + lane + 64 * i];                  // h2(k-3)
                hcf[2*i]   = pkrtz(t.x, t.y);
                hcf[2*i+1] = pkrtz(t.z, t.w);
            }
        }

        float* h0w = ws + (wp * 3 + 0) * HSZ;
        float* h1w = ws + (wp * 3 + 1) * HSZ;
        float* h2w = ws + (wp * 3 + 2) * HSZ;

        // ---- head: y(k-3) ----
        if (u == 0 && k >= 3) {
            float a = 0.0f;
#pragma unroll
            for (int j = 0; j < 8; ++j) a = FDOT2(wresh[j], hcf[j], a);
            a = wave_reduce(a) + bres0;
            if (lane == 0) out[k - 3] = sigm(a);
        }

        // ---- layer 0, t = k ----
        if (k < TSTEPS) {
            const float x0 = x[2 * k], x1 = x[2 * k + 1];
            float acc[4];
#pragma unroll
            for (int g = 0; g < 4; ++g) {
                float a = 0.0f;
#pragma unroll
                for (int j = 0; j < 8; ++j) a = FDOT2(w0h[g][j], haf[j], a);
                acc[g] = a;
            }
#pragma unroll
            for (int g = 0; g < 4; ++g)
                acc[g] = wave_reduce(acc[g]) + b0[g] + wx0a[g] * x0 + wx0b[g] * x1;
            const float ig = sigm(acc[0]), fg = sigm(acc[1]);
            const float gg = tanhf(acc[2]), og = sigm(acc[3]);
            c0 = fg * c0 + ig * gg;
            if (lane == 0) st_coh(h0w + u, og * tanhf(c0));
        }

        // ---- layer 1, t = k-1 ----
        if (k >= 1 && k <= TSTEPS) {
            float acc[4];
#pragma unroll
            for (int g = 0; g < 4; ++g) {
                float a = 0.0f;
#pragma unroll
                for (int j = 0; j < 8; ++j) {
                    a = FDOT2(wi1h[g][j], haf[j], a);
                    a = FDOT2(wh1h[g][j], hbf[j], a);
                }
                acc[g] = a;
            }
#pragma unroll
            for (int g = 0; g < 4; ++g) acc[g] = wave_reduce(acc[g]) + b1[g];
            const float ig = sigm(acc[0]), fg = sigm(acc[1]);
            const float gg = tanhf(acc[2]), og = sigm(acc[3]);
            c1 = fg * c1 + ig * gg;
            if (lane == 0) st_coh(h1w + u, og * tanhf(c1));
        }

        // ---- layer 2, t = k-2 ----
        if (k >= 2 && k <= TSTEPS + 1) {
            float acc[4];
#pragma unroll
            for (int g = 0; g < 4; ++g) {
                float a = 0.0f;
#pragma unroll
                for (int j = 0; j < 8; ++j) {
                    a = FDOT2(wi2h[g][j], hbf[j], a);
                    a = FDOT2(wh2h[g][j], hcf[j], a);
                }
                acc[g] = a;
            }
#pragma unroll
            for (int g = 0; g < 4; ++g) acc[g] = wave_reduce(acc[g]) + b2[g];
            const float ig = sigm(acc[0]), fg = sigm(acc[1]);
            const float gg = tanhf(acc[2]), og = sigm(acc[3]);
            c2 = fg * c2 + ig * gg;
            if (lane == 0) st_coh(h2w + u, og * tanhf(c2));
        }

        if (k < TSTEPS + 2) gbar(flags, ep++);
    }
}

extern "C" void kernel_launch(void* const* d_in, const int* in_sizes, int n_in,
                              void* d_out, int out_size, void* d_ws, size_t ws_size,
                              hipStream_t stream) {
    const float* x     = (const float*)d_in[0];
    const float* Wih0  = (const float*)d_in[1];
    const float* Whh0  = (const float*)d_in[2];
    const float* bih0  = (const float*)d_in[3];
    const float* bhh0  = (const float*)d_in[4];
    const float* Wih12 = (const float*)d_in[5];
    const float* Whh12 = (const float*)d_in[6];
    const float* bih12 = (const float*)d_in[7];
    const float* bhh12 = (const float*)d_in[8];
    const float* Wres  = (const float*)d_in[9];
    const float* bres  = (const float*)d_in[10];
    float* out = (float*)d_out;
    float* ws  = (float*)d_ws;

    lstm_persist<<<dim3(NBLK), dim3(NTHR), 0, stream>>>(
        x, Wih0, Whh0, bih0, bhh0, Wih12, Whh12, bih12, bhh12,
        Wres, bres, out, ws);
}

// Round 7
// 23656.197 us; speedup vs baseline: 17.5330x; 1.4467x over previous
//
#include <hip/hip_runtime.h>

#define HSZ 1024
#define TSTEPS 4096
#define NBLK 256
#define NTHR 256   // 4 waves/block x 256 blocks = 1024 waves == HSZ units
#define HV (HSZ / 4)

typedef _Float16 half2v __attribute__((ext_vector_type(2)));

#if __has_builtin(__builtin_amdgcn_fdot2)
#define FDOT2(a, b, c) __builtin_amdgcn_fdot2((a), (b), (c), false)
#else
__device__ __forceinline__ float FDOT2(half2v a, half2v b, float c) {
    return c + (float)a.x * (float)b.x + (float)a.y * (float)b.y;
}
#endif

__device__ __forceinline__ float wave_reduce(float v) {
#pragma unroll
    for (int off = 32; off; off >>= 1) v += __shfl_xor(v, off, 64);
    return v;
}

__device__ __forceinline__ float sigm(float x) { return 1.0f / (1.0f + __expf(-x)); }

// ---- agent-coherent (L3-level) accesses, no cache fences ----
__device__ __forceinline__ unsigned long long ld_coh64(const unsigned long long* p) {
    return __hip_atomic_load(p, __ATOMIC_RELAXED, __HIP_MEMORY_SCOPE_AGENT);
}
__device__ __forceinline__ void st_coh64(unsigned long long* p, unsigned long long v) {
    __hip_atomic_store(p, v, __ATOMIC_RELAXED, __HIP_MEMORY_SCOPE_AGENT);
}
// store one f16 h value (coherent 2-byte store)
__device__ __forceinline__ void st_h(unsigned short* p, float v) {
    _Float16 h = (_Float16)v;
    unsigned short b;
    __builtin_memcpy(&b, &h, 2);
    __hip_atomic_store(p, b, __ATOMIC_RELAXED, __HIP_MEMORY_SCOPE_AGENT);
}

// Pin packed-f16 weight into a VGPR (prevents load re-sinking).
#define PINH(h) asm volatile("" : "+v"(h))

// f32->half2 (init path, RNE per element)
__device__ __forceinline__ half2v cvt2(float a, float b) {
    half2v r; r.x = (_Float16)a; r.y = (_Float16)b; return r;
}

// ws byte layout:
//   [0, 12288)        h buffers: [2 parity][3 layer][1024] f16
//   12288 + j*64      arrival counters, j=0..7 (32 blocks each, blockIdx&7)
//   12800 + j*64      go-word replicas, j=0..7
// Poison 0xAAAAAAAA is a known constant -> counters/go need NO init:
//   counter target for epoch e = 0xAAAAAAAA + 32*e (monotone, no wrap),
//   go poison is negative < any epoch e >= 1.
#define CNT_OFF 12288
#define GO_OFF  12800

// Low-congestion device barrier: 256 arrival atomics striped over 8 lines;
// ONE wave (block 0) polls the 8 counters; everyone else polls 1 go-word
// with 1 lane. ~270 L3 poll loads per sweep vs 65536 in the flat scheme.
__device__ __forceinline__ void gbar(char* wsb, int e) {
    asm volatile("s_waitcnt vmcnt(0)" ::: "memory");  // own h stores acked at L3
    __syncthreads();                                   // whole block drained
    int* counters = (int*)(wsb + CNT_OFF);
    int* gos      = (int*)(wsb + GO_OFF);
    if (threadIdx.x == 0)
        __hip_atomic_fetch_add(counters + (blockIdx.x & 7) * 16, 1,
                               __ATOMIC_RELAXED, __HIP_MEMORY_SCOPE_AGENT);
    if (blockIdx.x == 0) {
        if (threadIdx.x < 64) {
            const int lane = threadIdx.x;
            const int target = (int)0xAAAAAAAAu + 32 * e;
            for (;;) {
                int ok = 1;
                if (lane < 8)
                    ok = (__hip_atomic_load(counters + lane * 16, __ATOMIC_RELAXED,
                                            __HIP_MEMORY_SCOPE_AGENT) - target) >= 0;
                if (__all(ok)) break;
                __builtin_amdgcn_s_sleep(1);
            }
            if (lane < 8)
                __hip_atomic_store(gos + lane * 16, e, __ATOMIC_RELAXED,
                                   __HIP_MEMORY_SCOPE_AGENT);
        }
    } else if (threadIdx.x == 0) {
        while (__hip_atomic_load(gos + (blockIdx.x & 7) * 16, __ATOMIC_RELAXED,
                                 __HIP_MEMORY_SCOPE_AGENT) < e)
            __builtin_amdgcn_s_sleep(1);
    }
    __syncthreads();
}

__global__ void __launch_bounds__(NTHR, 1) lstm_persist(
    const float* __restrict__ x,
    const float* __restrict__ Wih0, const float* __restrict__ Whh0,
    const float* __restrict__ bih0, const float* __restrict__ bhh0,
    const float* __restrict__ Wih12, const float* __restrict__ Whh12,
    const float* __restrict__ bih12, const float* __restrict__ bhh12,
    const float* __restrict__ Wres, const float* __restrict__ bres,
    float* __restrict__ out, float* __restrict__ ws_f)
{
    char* wsb = (char*)ws_f;
    const int lane = threadIdx.x & 63;
    const int u = blockIdx.x * (NTHR / 64) + (threadIdx.x >> 6);  // hidden unit

    __shared__ unsigned short hlds[3 * HSZ];  // 6 KB staged h (f16)

    // zero-init both parities of h (1536 qwords over the grid)
    {
        const int gid = blockIdx.x * NTHR + threadIdx.x;
        if (gid < 1536) st_coh64((unsigned long long*)wsb + gid, 0ull);
    }

    // ---- per-wave scalar constants ----
    float b0[4], b1[4], b2[4], wx0a[4], wx0b[4];
#pragma unroll
    for (int g = 0; g < 4; ++g) {
        const int r = g * HSZ + u;
        b0[g] = bih0[r] + bhh0[r];
        b1[g] = bih12[r] + bhh12[r];
        b2[g] = bih12[4 * HSZ + r] + bhh12[4 * HSZ + r];
        wx0a[g] = Wih0[2 * r];
        wx0b[g] = Wih0[2 * r + 1];
    }

    // ---- register-resident f16 weights: 20 rows x 1024 -> 160 half2/lane ----
    const float4* Whh0v = (const float4*)Whh0;
    const float4* Wih1v = (const float4*)Wih12;
    const float4* Whh1v = (const float4*)Whh12;
    const float4* Wih2v = (const float4*)(Wih12 + 4 * HSZ * HSZ);
    const float4* Whh2v = (const float4*)(Whh12 + 4 * HSZ * HSZ);

    half2v w0h[4][8], wi1h[4][8], wh1h[4][8], wi2h[4][8], wh2h[4][8];
#pragma unroll
    for (int g = 0; g < 4; ++g) {
        const size_t r = (size_t)(g * HSZ + u) * HV + lane;
#pragma unroll
        for (int i = 0; i < 4; ++i) {
            float4 t;
            t = Whh0v[r + 64 * i];  w0h[g][2*i] = cvt2(t.x,t.y);  w0h[g][2*i+1] = cvt2(t.z,t.w);
            t = Wih1v[r + 64 * i];  wi1h[g][2*i] = cvt2(t.x,t.y); wi1h[g][2*i+1] = cvt2(t.z,t.w);
            t = Whh1v[r + 64 * i];  wh1h[g][2*i] = cvt2(t.x,t.y); wh1h[g][2*i+1] = cvt2(t.z,t.w);
            t = Wih2v[r + 64 * i];  wi2h[g][2*i] = cvt2(t.x,t.y); wi2h[g][2*i+1] = cvt2(t.z,t.w);
            t = Whh2v[r + 64 * i];  wh2h[g][2*i] = cvt2(t.x,t.y); wh2h[g][2*i+1] = cvt2(t.z,t.w);
        }
    }
#pragma unroll
    for (int g = 0; g < 4; ++g)
#pragma unroll
        for (int j = 0; j < 8; ++j) {
            PINH(w0h[g][j]); PINH(wi1h[g][j]); PINH(wh1h[g][j]);
            PINH(wi2h[g][j]); PINH(wh2h[g][j]);
        }

    // head weights as f16 (used only by wave u==0)
    half2v wresh[8];
    {
        const float4* wr = (const float4*)Wres;
#pragma unroll
        for (int i = 0; i < 4; ++i) {
            float4 t = wr[lane + 64 * i];
            wresh[2*i] = cvt2(t.x, t.y); wresh[2*i+1] = cvt2(t.z, t.w);
        }
    }
    const float bres0 = bres[0];

    float c0 = 0.0f, c1 = 0.0f, c2 = 0.0f;
    gbar(wsb, 1);  // zero-init visible everywhere

    union Q { unsigned long long q; half2v h[2]; };

    // Wavefront pipeline: iter k -> layer0(t=k), layer1(k-1), layer2(k-2),
    // head y(k-3). One barrier per iteration (epoch k+2).
    for (int k = 0; k <= TSTEPS + 2; ++k) {
        const int wp = k & 1, rp = wp ^ 1;

        // cooperative coherent load of h(rp) -> LDS (6 KB, 3 qwords/thread)
        {
            const unsigned long long* src =
                (const unsigned long long*)(wsb + rp * 6144);
            unsigned long long* dst = (unsigned long long*)hlds;
#pragma unroll
            for (int j = 0; j < 3; ++j) {
                const int idx = j * NTHR + threadIdx.x;  // 768 qwords total
                dst[idx] = ld_coh64(src + idx);
            }
        }
        __syncthreads();

        // per-lane fragments straight from LDS (already f16)
        half2v haf[8], hbf[8], hcf[8];
        {
            const unsigned long long* hq = (const unsigned long long*)hlds;
#pragma unroll
            for (int i = 0; i < 4; ++i) {
                Q q;
                q.q = hq[lane + 64 * i];        // h0(k-1)
                haf[2*i] = q.h[0]; haf[2*i+1] = q.h[1];
                q.q = hq[256 + lane + 64 * i];  // h1(k-2)
                hbf[2*i] = q.h[0]; hbf[2*i+1] = q.h[1];
                q.q = hq[512 + lane + 64 * i];  // h2(k-3)
                hcf[2*i] = q.h[0]; hcf[2*i+1] = q.h[1];
            }
        }

        unsigned short* h0w = (unsigned short*)(wsb + wp * 6144);
        unsigned short* h1w = h0w + HSZ;
        unsigned short* h2w = h0w + 2 * HSZ;

        // ---- head: y(k-3) ----
        if (u == 0 && k >= 3) {
            float a = 0.0f;
#pragma unroll
            for (int j = 0; j < 8; ++j) a = FDOT2(wresh[j], hcf[j], a);
            a = wave_reduce(a) + bres0;
            if (lane == 0) out[k - 3] = sigm(a);
        }

        // ---- layer 0, t = k ----
        if (k < TSTEPS) {
            const float x0 = x[2 * k], x1 = x[2 * k + 1];
            float acc[4];
#pragma unroll
            for (int g = 0; g < 4; ++g) {
                float a = 0.0f;
#pragma unroll
                for (int j = 0; j < 8; ++j) a = FDOT2(w0h[g][j], haf[j], a);
                acc[g] = a;
            }
#pragma unroll
            for (int g = 0; g < 4; ++g)
                acc[g] = wave_reduce(acc[g]) + b0[g] + wx0a[g] * x0 + wx0b[g] * x1;
            const float ig = sigm(acc[0]), fg = sigm(acc[1]);
            const float gg = tanhf(acc[2]), og = sigm(acc[3]);
            c0 = fg * c0 + ig * gg;
            if (lane == 0) st_h(h0w + u, og * tanhf(c0));
        }

        // ---- layer 1, t = k-1 ----
        if (k >= 1 && k <= TSTEPS) {
            float acc[4];
#pragma unroll
            for (int g = 0; g < 4; ++g) {
                float a = 0.0f;
#pragma unroll
                for (int j = 0; j < 8; ++j) {
                    a = FDOT2(wi1h[g][j], haf[j], a);
                    a = FDOT2(wh1h[g][j], hbf[j], a);
                }
                acc[g] = a;
            }
#pragma unroll
            for (int g = 0; g < 4; ++g) acc[g] = wave_reduce(acc[g]) + b1[g];
            const float ig = sigm(acc[0]), fg = sigm(acc[1]);
            const float gg = tanhf(acc[2]), og = sigm(acc[3]);
            c1 = fg * c1 + ig * gg;
            if (lane == 0) st_h(h1w + u, og * tanhf(c1));
        }

        // ---- layer 2, t = k-2 ----
        if (k >= 2 && k <= TSTEPS + 1) {
            float acc[4];
#pragma unroll
            for (int g = 0; g < 4; ++g) {
                float a = 0.0f;
#pragma unroll
                for (int j = 0; j < 8; ++j) {
                    a = FDOT2(wi2h[g][j], hbf[j], a);
                    a = FDOT2(wh2h[g][j], hcf[j], a);
                }
                acc[g] = a;
            }
#pragma unroll
            for (int g = 0; g < 4; ++g) acc[g] = wave_reduce(acc[g]) + b2[g];
            const float ig = sigm(acc[0]), fg = sigm(acc[1]);
            const float gg = tanhf(acc[2]), og = sigm(acc[3]);
            c2 = fg * c2 + ig * gg;
            if (lane == 0) st_h(h2w + u, og * tanhf(c2));
        }

        if (k < TSTEPS + 2) gbar(wsb, k + 2);
    }
}

extern "C" void kernel_launch(void* const* d_in, const int* in_sizes, int n_in,
                              void* d_out, int out_size, void* d_ws, size_t ws_size,
                              hipStream_t stream) {
    const float* x     = (const float*)d_in[0];
    const float* Wih0  = (const float*)d_in[1];
    const float* Whh0  = (const float*)d_in[2];
    const float* bih0  = (const float*)d_in[3];
    const float* bhh0  = (const float*)d_in[4];
    const float* Wih12 = (const float*)d_in[5];
    const float* Whh12 = (const float*)d_in[6];
    const float* bih12 = (const float*)d_in[7];
    const float* bhh12 = (const float*)d_in[8];
    const float* Wres  = (const float*)d_in[9];
    const float* bres  = (const float*)d_in[10];
    float* out = (float*)d_out;
    float* ws  = (float*)d_ws;

    lstm_persist<<<dim3(NBLK), dim3(NTHR), 0, stream>>>(
        x, Wih0, Whh0, bih0, bhh0, Wih12, Whh12, bih12, bhh12,
        Wres, bres, out, ws);
}

// Round 8
// 20425.630 us; speedup vs baseline: 20.3060x; 1.1582x over previous
//
#include <hip/hip_runtime.h>

#define HSZ 1024
#define TSTEPS 4096
#define NBLK 256
#define NTHR 256   // 4 waves/block x 256 blocks = 1024 waves == HSZ units
#define HV (HSZ / 4)
#define REP_BYTES 24576  // one replica: [2 parity][3 layer][1024] tagged dwords

typedef _Float16 half2v __attribute__((ext_vector_type(2)));

#if __has_builtin(__builtin_amdgcn_fdot2)
#define FDOT2(a, b, c) __builtin_amdgcn_fdot2((a), (b), (c), false)
#else
__device__ __forceinline__ float FDOT2(half2v a, half2v b, float c) {
    return c + (float)a.x * (float)b.x + (float)a.y * (float)b.y;
}
#endif

__device__ __forceinline__ float wave_reduce(float v) {
#pragma unroll
    for (int off = 32; off; off >>= 1) v += __shfl_xor(v, off, 64);
    return v;
}

__device__ __forceinline__ float sigm(float x) { return 1.0f / (1.0f + __expf(-x)); }

// ---- agent-coherent (L3-level) accesses, no cache fences ----
__device__ __forceinline__ unsigned long long ld_coh64(const unsigned long long* p) {
    return __hip_atomic_load(p, __ATOMIC_RELAXED, __HIP_MEMORY_SCOPE_AGENT);
}
__device__ __forceinline__ void st_coh32(unsigned* p, unsigned v) {
    __hip_atomic_store(p, v, __ATOMIC_RELAXED, __HIP_MEMORY_SCOPE_AGENT);
}

__device__ __forceinline__ unsigned f16bits(float v) {
    _Float16 h = (_Float16)v;
    unsigned short b;
    __builtin_memcpy(&b, &h, 2);
    return (unsigned)b;
}

// Pin packed-f16 weight into a VGPR (prevents load re-sinking).
#define PINH(h) asm volatile("" : "+v"(h))

// f32->half2 (init path, RNE per element)
__device__ __forceinline__ half2v cvt2(float a, float b) {
    half2v r; r.x = (_Float16)a; r.y = (_Float16)b; return r;
}

// Self-synchronizing tagged h exchange, NO global barrier:
//   word = (tag16 << 16) | f16(h).  Iter k: reads parity (k&1)^1 expecting
//   tag k (stored at iter k-1), writes parity k&1 with tag k+1.
//   Init fills parity 1 with tag 0 (= h(-1..)=0).  Poison tag 0xAAAA never
//   matches (tags <= 4099).  Skew between blocks is bounded to <=1 iter by
//   the read-all -> syncthreads -> store order inside each iteration.
//   The buffer is replicated nrep times; block b polls replica b%nrep,
//   producers store to all replicas (fire-and-forget).

__global__ void __launch_bounds__(NTHR, 1) lstm_persist(
    const float* __restrict__ x,
    const float* __restrict__ Wih0, const float* __restrict__ Whh0,
    const float* __restrict__ bih0, const float* __restrict__ bhh0,
    const float* __restrict__ Wih12, const float* __restrict__ Whh12,
    const float* __restrict__ bih12, const float* __restrict__ bhh12,
    const float* __restrict__ Wres, const float* __restrict__ bres,
    float* __restrict__ out, float* __restrict__ ws_f, int nrep)
{
    char* wsb = (char*)ws_f;
    const int lane = threadIdx.x & 63;
    const int u = blockIdx.x * (NTHR / 64) + (threadIdx.x >> 6);  // hidden unit
    const int tid = threadIdx.x;

    __shared__ unsigned short hlds[3 * HSZ];  // 6 KB staged h (f16)

    // ---- init: parity 1 of every replica = tag 0, value 0 ----
    {
        const int gid = blockIdx.x * NTHR + tid;
        if (gid < nrep * 3072) {
            const int rep = gid / 3072, d = gid % 3072;
            st_coh32((unsigned*)(wsb + rep * REP_BYTES) + 3072 + d, 0u);
        }
    }

    // ---- per-wave scalar constants ----
    float b0[4], b1[4], b2[4], wx0a[4], wx0b[4];
#pragma unroll
    for (int g = 0; g < 4; ++g) {
        const int r = g * HSZ + u;
        b0[g] = bih0[r] + bhh0[r];
        b1[g] = bih12[r] + bhh12[r];
        b2[g] = bih12[4 * HSZ + r] + bhh12[4 * HSZ + r];
        wx0a[g] = Wih0[2 * r];
        wx0b[g] = Wih0[2 * r + 1];
    }

    // ---- register-resident f16 weights: 20 rows x 1024 -> 160 half2/lane ----
    const float4* Whh0v = (const float4*)Whh0;
    const float4* Wih1v = (const float4*)Wih12;
    const float4* Whh1v = (const float4*)Whh12;
    const float4* Wih2v = (const float4*)(Wih12 + 4 * HSZ * HSZ);
    const float4* Whh2v = (const float4*)(Whh12 + 4 * HSZ * HSZ);

    half2v w0h[4][8], wi1h[4][8], wh1h[4][8], wi2h[4][8], wh2h[4][8];
#pragma unroll
    for (int g = 0; g < 4; ++g) {
        const size_t r = (size_t)(g * HSZ + u) * HV + lane;
#pragma unroll
        for (int i = 0; i < 4; ++i) {
            float4 t;
            t = Whh0v[r + 64 * i];  w0h[g][2*i] = cvt2(t.x,t.y);  w0h[g][2*i+1] = cvt2(t.z,t.w);
            t = Wih1v[r + 64 * i];  wi1h[g][2*i] = cvt2(t.x,t.y); wi1h[g][2*i+1] = cvt2(t.z,t.w);
            t = Whh1v[r + 64 * i];  wh1h[g][2*i] = cvt2(t.x,t.y); wh1h[g][2*i+1] = cvt2(t.z,t.w);
            t = Wih2v[r + 64 * i];  wi2h[g][2*i] = cvt2(t.x,t.y); wi2h[g][2*i+1] = cvt2(t.z,t.w);
            t = Whh2v[r + 64 * i];  wh2h[g][2*i] = cvt2(t.x,t.y); wh2h[g][2*i+1] = cvt2(t.z,t.w);
        }
    }
#pragma unroll
    for (int g = 0; g < 4; ++g)
#pragma unroll
        for (int j = 0; j < 8; ++j) {
            PINH(w0h[g][j]); PINH(wi1h[g][j]); PINH(wh1h[g][j]);
            PINH(wi2h[g][j]); PINH(wh2h[g][j]);
        }

    // head weights as f16 (used only by wave u==0)
    half2v wresh[8];
    {
        const float4* wr = (const float4*)Wres;
#pragma unroll
        for (int i = 0; i < 4; ++i) {
            float4 t = wr[lane + 64 * i];
            wresh[2*i] = cvt2(t.x, t.y); wresh[2*i+1] = cvt2(t.z, t.w);
        }
    }
    const float bres0 = bres[0];

    // Drain init stores (and weight loads) so no late init write can clobber
    // a live tagged word after other blocks advance.
    asm volatile("s_waitcnt vmcnt(0)" ::: "memory");
    __syncthreads();

    const unsigned long long* Tmyq =
        (const unsigned long long*)(wsb + (blockIdx.x % nrep) * REP_BYTES);

    float c0 = 0.0f, c1 = 0.0f, c2 = 0.0f;
    union Q { unsigned long long q; half2v h[2]; };

    // Wavefront pipeline: iter k -> layer0(t=k), layer1(k-1), layer2(k-2),
    // head y(k-3). No barrier: tagged-data flow control.
    for (int k = 0; k <= TSTEPS + 2; ++k) {
        const int wp = k & 1, rp = wp ^ 1;
        const unsigned e = (unsigned)k;  // expected tag this iteration

        // ---- poll own replica: 6 qwords (12 tagged dwords) per thread ----
        {
            const unsigned long long* Tq = Tmyq + rp * 1536;
            unsigned long long q[6];
            unsigned need = 0x3F;
            for (;;) {
#pragma unroll
                for (int m = 0; m < 6; ++m)
                    if (need & (1u << m))
                        q[m] = ld_coh64(Tq + (m >> 1) * 512 + 2 * tid + (m & 1));
#pragma unroll
                for (int m = 0; m < 6; ++m)
                    if (need & (1u << m)) {
                        const unsigned t0 = ((unsigned)q[m]) >> 16;
                        const unsigned t1 = (unsigned)(q[m] >> 48);
                        if (t0 == e && t1 == e) need &= ~(1u << m);
                    }
                if (!need) break;
                __builtin_amdgcn_s_sleep(1);
            }
            // scatter to LDS: pack pairs of low-16 halves
#pragma unroll
            for (int l = 0; l < 3; ++l) {
                const unsigned d0 = (unsigned)q[2*l], d1 = (unsigned)(q[2*l] >> 32);
                const unsigned d2 = (unsigned)q[2*l+1], d3 = (unsigned)(q[2*l+1] >> 32);
                const unsigned pk0 = (d1 << 16) | (d0 & 0xFFFFu);
                const unsigned pk1 = (d3 << 16) | (d2 & 0xFFFFu);
                ((unsigned long long*)hlds)[l * 256 + tid] =
                    (unsigned long long)pk0 | ((unsigned long long)pk1 << 32);
            }
        }
        __syncthreads();  // all polls done + LDS populated

        // ---- per-lane fragments from LDS ----
        half2v haf[8], hbf[8], hcf[8];
        {
            const unsigned long long* hq = (const unsigned long long*)hlds;
#pragma unroll
            for (int i = 0; i < 4; ++i) {
                Q q;
                q.q = hq[lane + 64 * i];        // h0(k-1)
                haf[2*i] = q.h[0]; haf[2*i+1] = q.h[1];
                q.q = hq[256 + lane + 64 * i];  // h1(k-2)
                hbf[2*i] = q.h[0]; hbf[2*i+1] = q.h[1];
                q.q = hq[512 + lane + 64 * i];  // h2(k-3)
                hcf[2*i] = q.h[0]; hcf[2*i+1] = q.h[1];
            }
        }

        // ---- head: y(k-3) ----
        if (u == 0 && k >= 3) {
            float a = 0.0f;
#pragma unroll
            for (int j = 0; j < 8; ++j) a = FDOT2(wresh[j], hcf[j], a);
            a = wave_reduce(a) + bres0;
            if (lane == 0) out[k - 3] = sigm(a);
        }

        float h0v = 0.0f, h1v = 0.0f, h2v = 0.0f;

        // ---- layer 0, t = k ----
        if (k < TSTEPS) {
            const float x0 = x[2 * k], x1 = x[2 * k + 1];
            float acc[4];
#pragma unroll
            for (int g = 0; g < 4; ++g) {
                float a = 0.0f;
#pragma unroll
                for (int j = 0; j < 8; ++j) a = FDOT2(w0h[g][j], haf[j], a);
                acc[g] = a;
            }
#pragma unroll
            for (int g = 0; g < 4; ++g)
                acc[g] = wave_reduce(acc[g]) + b0[g] + wx0a[g] * x0 + wx0b[g] * x1;
            const float ig = sigm(acc[0]), fg = sigm(acc[1]);
            const float gg = tanhf(acc[2]), og = sigm(acc[3]);
            c0 = fg * c0 + ig * gg;
            h0v = og * tanhf(c0);
        }

        // ---- layer 1, t = k-1 ----
        if (k >= 1 && k <= TSTEPS) {
            float acc[4];
#pragma unroll
            for (int g = 0; g < 4; ++g) {
                float a = 0.0f;
#pragma unroll
                for (int j = 0; j < 8; ++j) {
                    a = FDOT2(wi1h[g][j], haf[j], a);
                    a = FDOT2(wh1h[g][j], hbf[j], a);
                }
                acc[g] = a;
            }
#pragma unroll
            for (int g = 0; g < 4; ++g) acc[g] = wave_reduce(acc[g]) + b1[g];
            const float ig = sigm(acc[0]), fg = sigm(acc[1]);
            const float gg = tanhf(acc[2]), og = sigm(acc[3]);
            c1 = fg * c1 + ig * gg;
            h1v = og * tanhf(c1);
        }

        // ---- layer 2, t = k-2 ----
        if (k >= 2 && k <= TSTEPS + 1) {
            float acc[4];
#pragma unroll
            for (int g = 0; g < 4; ++g) {
                float a = 0.0f;
#pragma unroll
                for (int j = 0; j < 8; ++j) {
                    a = FDOT2(wi2h[g][j], hbf[j], a);
                    a = FDOT2(wh2h[g][j], hcf[j], a);
                }
                acc[g] = a;
            }
#pragma unroll
            for (int g = 0; g < 4; ++g) acc[g] = wave_reduce(acc[g]) + b2[g];
            const float ig = sigm(acc[0]), fg = sigm(acc[1]);
            const float gg = tanhf(acc[2]), og = sigm(acc[3]);
            c2 = fg * c2 + ig * gg;
            h2v = og * tanhf(c2);
        }

        // ---- publish tagged h to all replicas (fire-and-forget) ----
        if (lane == 0 && k <= TSTEPS + 1) {
            const unsigned tg = (unsigned)(k + 1) << 16;
            const unsigned w0b = tg | f16bits(h0v);
            const unsigned w1b = tg | f16bits(h1v);
            const unsigned w2b = tg | f16bits(h2v);
            for (int rep = 0; rep < nrep; ++rep) {
                unsigned* Tw = (unsigned*)(wsb + rep * REP_BYTES) + wp * 3072;
                st_coh32(Tw + u, w0b);
                st_coh32(Tw + 1024 + u, w1b);
                st_coh32(Tw + 2048 + u, w2b);
            }
        }

        __syncthreads();  // protect LDS before next iteration's scatter
    }
}

extern "C" void kernel_launch(void* const* d_in, const int* in_sizes, int n_in,
                              void* d_out, int out_size, void* d_ws, size_t ws_size,
                              hipStream_t stream) {
    const float* x     = (const float*)d_in[0];
    const float* Wih0  = (const float*)d_in[1];
    const float* Whh0  = (const float*)d_in[2];
    const float* bih0  = (const float*)d_in[3];
    const float* bhh0  = (const float*)d_in[4];
    const float* Wih12 = (const float*)d_in[5];
    const float* Whh12 = (const float*)d_in[6];
    const float* bih12 = (const float*)d_in[7];
    const float* bhh12 = (const float*)d_in[8];
    const float* Wres  = (const float*)d_in[9];
    const float* bres  = (const float*)d_in[10];
    float* out = (float*)d_out;
    float* ws  = (float*)d_ws;

    int nrep = (int)(ws_size / REP_BYTES);
    if (nrep > 8) nrep = 8;
    if (nrep < 1) nrep = 1;

    lstm_persist<<<dim3(NBLK), dim3(NTHR), 0, stream>>>(
        x, Wih0, Whh0, bih0, bhh0, Wih12, Whh12, bih12, bhh12,
        Wres, bres, out, ws, nrep);
}

// Round 9
// 18773.604 us; speedup vs baseline: 22.0929x; 1.0880x over previous
//
#include <hip/hip_runtime.h>

#define HSZ 1024
#define TSTEPS 4096
#define NBLK 256
#define NTHR 256   // 4 waves/block x 256 blocks = 1024 waves == HSZ units
#define HV (HSZ / 4)
#define REP_BYTES 24576  // one replica: [2 parity][3 array][1024 tagged dwords]

typedef _Float16 half2v __attribute__((ext_vector_type(2)));

#if __has_builtin(__builtin_amdgcn_fdot2)
#define FDOT2(a, b, c) __builtin_amdgcn_fdot2((a), (b), (c), false)
#else
__device__ __forceinline__ float FDOT2(half2v a, half2v b, float c) {
    return c + (float)a.x * (float)b.x + (float)a.y * (float)b.y;
}
#endif

__device__ __forceinline__ float wave_reduce(float v) {
#pragma unroll
    for (int off = 32; off; off >>= 1) v += __shfl_xor(v, off, 64);
    return v;
}

__device__ __forceinline__ float sigm(float x) { return 1.0f / (1.0f + __expf(-x)); }

// ---- agent-coherent (L3-level) accesses, no cache fences ----
__device__ __forceinline__ unsigned long long ld_coh64(const unsigned long long* p) {
    return __hip_atomic_load(p, __ATOMIC_RELAXED, __HIP_MEMORY_SCOPE_AGENT);
}
__device__ __forceinline__ void st_coh32(unsigned* p, unsigned v) {
    __hip_atomic_store(p, v, __ATOMIC_RELAXED, __HIP_MEMORY_SCOPE_AGENT);
}

__device__ __forceinline__ unsigned f16bits(float v) {
    _Float16 h = (_Float16)v;
    unsigned short b;
    __builtin_memcpy(&b, &h, 2);
    return (unsigned)b;
}

// Pin packed-f16 weight into a VGPR (prevents load re-sinking).
#define PINH(h) asm volatile("" : "+v"(h))

// f32->half2 (init path, RNE per element)
__device__ __forceinline__ half2v cvt2(float a, float b) {
    half2v r; r.x = (_Float16)a; r.y = (_Float16)b; return r;
}

// Poll one tagged h-array (1024 dwords = 512 qwords; 2 qwords/thread) until
// all 4 tags match epoch e, then pack the two f16 payload pairs into LDS.
// Full-array coverage per block each iteration is the safety invariant.
__device__ __forceinline__ void poll_array(const unsigned long long* Tq,
                                           unsigned e, int tid, unsigned* lds32) {
    unsigned long long q0 = 0, q1 = 0;
    unsigned need = 3;
    for (;;) {
        if (need & 1) q0 = ld_coh64(Tq + tid);
        if (need & 2) q1 = ld_coh64(Tq + 256 + tid);
        if (need & 1)
            if ((((unsigned)q0) >> 16) == e && ((unsigned)(q0 >> 48)) == e)
                need &= ~1u;
        if (need & 2)
            if ((((unsigned)q1) >> 16) == e && ((unsigned)(q1 >> 48)) == e)
                need &= ~2u;
        if (!need) break;
        __builtin_amdgcn_s_sleep(1);
    }
    lds32[tid]       = (((unsigned)(q0 >> 32)) << 16) | ((unsigned)q0 & 0xFFFFu);
    lds32[tid + 256] = (((unsigned)(q1 >> 32)) << 16) | ((unsigned)q1 & 0xFFFFu);
}

__global__ void __launch_bounds__(NTHR, 1) lstm_persist(
    const float* __restrict__ x,
    const float* __restrict__ Wih0, const float* __restrict__ Whh0,
    const float* __restrict__ bih0, const float* __restrict__ bhh0,
    const float* __restrict__ Wih12, const float* __restrict__ Whh12,
    const float* __restrict__ bih12, const float* __restrict__ bhh12,
    const float* __restrict__ Wres, const float* __restrict__ bres,
    float* __restrict__ out, float* __restrict__ ws_f, int nrep)
{
    char* wsb = (char*)ws_f;
    const int lane = threadIdx.x & 63;
    const int u = blockIdx.x * (NTHR / 64) + (threadIdx.x >> 6);  // hidden unit
    const int tid = threadIdx.x;

    __shared__ unsigned long long lds_h[3][256];  // 3 x 1024 f16, 8B-aligned

    // ---- init: parity 1 of every replica = tag 0, value 0 ----
    {
        const int gid = blockIdx.x * NTHR + tid;
        if (gid < nrep * 3072) {
            const int rep = gid / 3072, d = gid % 3072;
            st_coh32((unsigned*)(wsb + rep * REP_BYTES) + 3072 + d, 0u);
        }
    }

    // ---- per-wave scalar constants ----
    float b0[4], b1[4], b2[4], wx0a[4], wx0b[4];
#pragma unroll
    for (int g = 0; g < 4; ++g) {
        const int r = g * HSZ + u;
        b0[g] = bih0[r] + bhh0[r];
        b1[g] = bih12[r] + bhh12[r];
        b2[g] = bih12[4 * HSZ + r] + bhh12[4 * HSZ + r];
        wx0a[g] = Wih0[2 * r];
        wx0b[g] = Wih0[2 * r + 1];
    }

    // ---- register-resident f16 weights: 20 rows x 1024 -> 160 half2/lane ----
    const float4* Whh0v = (const float4*)Whh0;
    const float4* Wih1v = (const float4*)Wih12;
    const float4* Whh1v = (const float4*)Whh12;
    const float4* Wih2v = (const float4*)(Wih12 + 4 * HSZ * HSZ);
    const float4* Whh2v = (const float4*)(Whh12 + 4 * HSZ * HSZ);

    half2v w0h[4][8], wi1h[4][8], wh1h[4][8], wi2h[4][8], wh2h[4][8];
#pragma unroll
    for (int g = 0; g < 4; ++g) {
        const size_t r = (size_t)(g * HSZ + u) * HV + lane;
#pragma unroll
        for (int i = 0; i < 4; ++i) {
            float4 t;
            t = Whh0v[r + 64 * i];  w0h[g][2*i] = cvt2(t.x,t.y);  w0h[g][2*i+1] = cvt2(t.z,t.w);
            t = Wih1v[r + 64 * i];  wi1h[g][2*i] = cvt2(t.x,t.y); wi1h[g][2*i+1] = cvt2(t.z,t.w);
            t = Whh1v[r + 64 * i];  wh1h[g][2*i] = cvt2(t.x,t.y); wh1h[g][2*i+1] = cvt2(t.z,t.w);
            t = Wih2v[r + 64 * i];  wi2h[g][2*i] = cvt2(t.x,t.y); wi2h[g][2*i+1] = cvt2(t.z,t.w);
            t = Whh2v[r + 64 * i];  wh2h[g][2*i] = cvt2(t.x,t.y); wh2h[g][2*i+1] = cvt2(t.z,t.w);
        }
    }
#pragma unroll
    for (int g = 0; g < 4; ++g)
#pragma unroll
        for (int j = 0; j < 8; ++j) {
            PINH(w0h[g][j]); PINH(wi1h[g][j]); PINH(wh1h[g][j]);
            PINH(wi2h[g][j]); PINH(wh2h[g][j]);
        }

    // head weights as f16 (used only by wave u==0)
    half2v wresh[8];
    {
        const float4* wr = (const float4*)Wres;
#pragma unroll
        for (int i = 0; i < 4; ++i) {
            float4 t = wr[lane + 64 * i];
            wresh[2*i] = cvt2(t.x, t.y); wresh[2*i+1] = cvt2(t.z, t.w);
        }
    }
    const float bres0 = bres[0];

    // Drain init stores so no late init write can clobber a live tagged word.
    asm volatile("s_waitcnt vmcnt(0)" ::: "memory");
    __syncthreads();

    const unsigned long long* Tmyq =
        (const unsigned long long*)(wsb + (blockIdx.x % nrep) * REP_BYTES);

    float c0 = 0.0f, c1 = 0.0f, c2 = 0.0f;
    union Q { unsigned long long q; half2v h[2]; };

    // Wavefront pipeline with per-layer early publish:
    //   iter k: poll h0 -> L0(t=k) -> publish h0 | poll h1 -> L1(k-1) ->
    //   publish h1 | poll h2 -> head(k-3), L2(k-2) -> publish h2.
    // Each publish(tag k+1, array l) is ~1 compute-phase ahead of its
    // consumers' iter-(k+1) poll -> store flight fully hidden.
    for (int k = 0; k <= TSTEPS + 2; ++k) {
        const int wp = k & 1, rp = wp ^ 1;
        const unsigned e = (unsigned)k;
        const unsigned long long* Trp = Tmyq + rp * 1536;
        const bool pub = (k <= TSTEPS + 1);
        const unsigned tg = (unsigned)(k + 1) << 16;

        // ================= layer 0 =================
        poll_array(Trp, e, tid, (unsigned*)lds_h[0]);
        __syncthreads();

        half2v haf[8];
#pragma unroll
        for (int i = 0; i < 4; ++i) {
            Q q; q.q = lds_h[0][lane + 64 * i];
            haf[2*i] = q.h[0]; haf[2*i+1] = q.h[1];
        }

        float h0v = 0.0f;
        if (k < TSTEPS) {
            const float x0 = x[2 * k], x1 = x[2 * k + 1];
            float acc[4];
#pragma unroll
            for (int g = 0; g < 4; ++g) {
                float a = 0.0f;
#pragma unroll
                for (int j = 0; j < 8; ++j) a = FDOT2(w0h[g][j], haf[j], a);
                acc[g] = a;
            }
#pragma unroll
            for (int g = 0; g < 4; ++g)
                acc[g] = wave_reduce(acc[g]) + b0[g] + wx0a[g] * x0 + wx0b[g] * x1;
            const float ig = sigm(acc[0]), fg = sigm(acc[1]);
            const float gg = tanhf(acc[2]), og = sigm(acc[3]);
            c0 = fg * c0 + ig * gg;
            h0v = og * tanhf(c0);
        }
        if (lane == 0 && pub) {
            const unsigned wb = tg | f16bits(h0v);
            for (int rep = 0; rep < nrep; ++rep)
                st_coh32((unsigned*)(wsb + rep * REP_BYTES) + wp * 3072 + u, wb);
        }

        // ================= layer 1 =================
        poll_array(Trp + 512, e, tid, (unsigned*)lds_h[1]);
        __syncthreads();

        half2v hbf[8];
#pragma unroll
        for (int i = 0; i < 4; ++i) {
            Q q; q.q = lds_h[1][lane + 64 * i];
            hbf[2*i] = q.h[0]; hbf[2*i+1] = q.h[1];
        }

        float h1v = 0.0f;
        if (k >= 1 && k <= TSTEPS) {
            float acc[4];
#pragma unroll
            for (int g = 0; g < 4; ++g) {
                float a = 0.0f;
#pragma unroll
                for (int j = 0; j < 8; ++j) {
                    a = FDOT2(wi1h[g][j], haf[j], a);
                    a = FDOT2(wh1h[g][j], hbf[j], a);
                }
                acc[g] = a;
            }
#pragma unroll
            for (int g = 0; g < 4; ++g) acc[g] = wave_reduce(acc[g]) + b1[g];
            const float ig = sigm(acc[0]), fg = sigm(acc[1]);
            const float gg = tanhf(acc[2]), og = sigm(acc[3]);
            c1 = fg * c1 + ig * gg;
            h1v = og * tanhf(c1);
        }
        if (lane == 0 && pub) {
            const unsigned wb = tg | f16bits(h1v);
            for (int rep = 0; rep < nrep; ++rep)
                st_coh32((unsigned*)(wsb + rep * REP_BYTES) + wp * 3072 + 1024 + u, wb);
        }

        // ================= layer 2 + head =================
        poll_array(Trp + 1024, e, tid, (unsigned*)lds_h[2]);
        __syncthreads();

        half2v hcf[8];
#pragma unroll
        for (int i = 0; i < 4; ++i) {
            Q q; q.q = lds_h[2][lane + 64 * i];
            hcf[2*i] = q.h[0]; hcf[2*i+1] = q.h[1];
        }

        if (u == 0 && k >= 3) {
            float a = 0.0f;
#pragma unroll
            for (int j = 0; j < 8; ++j) a = FDOT2(wresh[j], hcf[j], a);
            a = wave_reduce(a) + bres0;
            if (lane == 0) out[k - 3] = sigm(a);
        }

        float h2v = 0.0f;
        if (k >= 2 && k <= TSTEPS + 1) {
            float acc[4];
#pragma unroll
            for (int g = 0; g < 4; ++g) {
                float a = 0.0f;
#pragma unroll
                for (int j = 0; j < 8; ++j) {
                    a = FDOT2(wi2h[g][j], hbf[j], a);
                    a = FDOT2(wh2h[g][j], hcf[j], a);
                }
                acc[g] = a;
            }
#pragma unroll
            for (int g = 0; g < 4; ++g) acc[g] = wave_reduce(acc[g]) + b2[g];
            const float ig = sigm(acc[0]), fg = sigm(acc[1]);
            const float gg = tanhf(acc[2]), og = sigm(acc[3]);
            c2 = fg * c2 + ig * gg;
            h2v = og * tanhf(c2);
        }
        if (lane == 0 && pub) {
            const unsigned wb = tg | f16bits(h2v);
            for (int rep = 0; rep < nrep; ++rep)
                st_coh32((unsigned*)(wsb + rep * REP_BYTES) + wp * 3072 + 2048 + u, wb);
        }
    }
}

extern "C" void kernel_launch(void* const* d_in, const int* in_sizes, int n_in,
                              void* d_out, int out_size, void* d_ws, size_t ws_size,
                              hipStream_t stream) {
    const float* x     = (const float*)d_in[0];
    const float* Wih0  = (const float*)d_in[1];
    const float* Whh0  = (const float*)d_in[2];
    const float* bih0  = (const float*)d_in[3];
    const float* bhh0  = (const float*)d_in[4];
    const float* Wih12 = (const float*)d_in[5];
    const float* Whh12 = (const float*)d_in[6];
    const float* bih12 = (const float*)d_in[7];
    const float* bhh12 = (const float*)d_in[8];
    const float* Wres  = (const float*)d_in[9];
    const float* bres  = (const float*)d_in[10];
    float* out = (float*)d_out;
    float* ws  = (float*)d_ws;

    int nrep = (int)(ws_size / REP_BYTES);
    if (nrep > 8) nrep = 8;
    if (nrep < 1) nrep = 1;

    lstm_persist<<<dim3(NBLK), dim3(NTHR), 0, stream>>>(
        x, Wih0, Whh0, bih0, bhh0, Wih12, Whh12, bih12, bhh12,
        Wres, bres, out, ws, nrep);
}

// Round 10
// 17449.875 us; speedup vs baseline: 23.7688x; 1.0759x over previous
//
#include <hip/hip_runtime.h>

#define HSZ 1024
#define TSTEPS 4096
#define NBLK 256
#define NTHR 256   // 4 waves/block x 256 blocks = 1024 waves == HSZ units
#define HV (HSZ / 4)
#define REP_BYTES 24576  // one replica: [2 parity][3 array][1024 tagged dwords]

typedef _Float16 half2v __attribute__((ext_vector_type(2)));

#if __has_builtin(__builtin_amdgcn_fdot2)
#define FDOT2(a, b, c) __builtin_amdgcn_fdot2((a), (b), (c), false)
#else
__device__ __forceinline__ float FDOT2(half2v a, half2v b, float c) {
    return c + (float)a.x * (float)b.x + (float)a.y * (float)b.y;
}
#endif

__device__ __forceinline__ float wave_reduce(float v) {
#pragma unroll
    for (int off = 32; off; off >>= 1) v += __shfl_xor(v, off, 64);
    return v;
}

__device__ __forceinline__ float sigm(float x) { return 1.0f / (1.0f + __expf(-x)); }

// ---- agent-coherent (L3-level) accesses, no cache fences ----
__device__ __forceinline__ unsigned long long ld_coh64(const unsigned long long* p) {
    return __hip_atomic_load(p, __ATOMIC_RELAXED, __HIP_MEMORY_SCOPE_AGENT);
}
__device__ __forceinline__ void st_coh32(unsigned* p, unsigned v) {
    __hip_atomic_store(p, v, __ATOMIC_RELAXED, __HIP_MEMORY_SCOPE_AGENT);
}

__device__ __forceinline__ unsigned f16bits(float v) {
    _Float16 h = (_Float16)v;
    unsigned short b;
    __builtin_memcpy(&b, &h, 2);
    return (unsigned)b;
}

// Pin packed-f16 weight into a VGPR (prevents load re-sinking).
#define PINH(h) asm volatile("" : "+v"(h))

// f32->half2 (init path, RNE per element)
__device__ __forceinline__ half2v cvt2(float a, float b) {
    half2v r; r.x = (_Float16)a; r.y = (_Float16)b; return r;
}

// ---- split-phase poll: issue loads early, check late (flight hides under
// compute of the preceding layer). Retry loop only on stale first attempt. ----
struct PollQ { unsigned long long q0, q1; };

__device__ __forceinline__ PollQ poll_issue(const unsigned long long* Tq, int tid) {
    PollQ p;
    p.q0 = ld_coh64(Tq + tid);
    p.q1 = ld_coh64(Tq + 256 + tid);
    return p;
}

__device__ __forceinline__ void poll_complete(PollQ p, const unsigned long long* Tq,
                                              unsigned e, int tid, unsigned* lds32) {
    for (;;) {
        const bool ok0 = ((((unsigned)p.q0) >> 16) == e) && (((unsigned)(p.q0 >> 48)) == e);
        const bool ok1 = ((((unsigned)p.q1) >> 16) == e) && (((unsigned)(p.q1 >> 48)) == e);
        if (ok0 && ok1) break;
        __builtin_amdgcn_s_sleep(1);
        p.q0 = ld_coh64(Tq + tid);
        p.q1 = ld_coh64(Tq + 256 + tid);
    }
    lds32[tid]       = (((unsigned)(p.q0 >> 32)) << 16) | ((unsigned)p.q0 & 0xFFFFu);
    lds32[tid + 256] = (((unsigned)(p.q1 >> 32)) << 16) | ((unsigned)p.q1 & 0xFFFFu);
}

__global__ void __launch_bounds__(NTHR, 1) lstm_persist(
    const float* __restrict__ x,
    const float* __restrict__ Wih0, const float* __restrict__ Whh0,
    const float* __restrict__ bih0, const float* __restrict__ bhh0,
    const float* __restrict__ Wih12, const float* __restrict__ Whh12,
    const float* __restrict__ bih12, const float* __restrict__ bhh12,
    const float* __restrict__ Wres, const float* __restrict__ bres,
    float* __restrict__ out, float* __restrict__ ws_f, int nrep)
{
    char* wsb = (char*)ws_f;
    const int lane = threadIdx.x & 63;
    const int u = blockIdx.x * (NTHR / 64) + (threadIdx.x >> 6);  // hidden unit
    const int tid = threadIdx.x;

    __shared__ unsigned long long lds_h[3][256];  // 3 x 1024 f16

    // ---- init: parity 1 of every replica = tag 0, value 0 ----
    {
        const int gid = blockIdx.x * NTHR + tid;
        if (gid < nrep * 3072) {
            const int rep = gid / 3072, d = gid % 3072;
            st_coh32((unsigned*)(wsb + rep * REP_BYTES) + 3072 + d, 0u);
        }
    }

    // ---- per-wave scalar constants ----
    float b0[4], b1[4], b2[4], wx0a[4], wx0b[4];
#pragma unroll
    for (int g = 0; g < 4; ++g) {
        const int r = g * HSZ + u;
        b0[g] = bih0[r] + bhh0[r];
        b1[g] = bih12[r] + bhh12[r];
        b2[g] = bih12[4 * HSZ + r] + bhh12[4 * HSZ + r];
        wx0a[g] = Wih0[2 * r];
        wx0b[g] = Wih0[2 * r + 1];
    }

    // ---- register-resident f16 weights: 20 rows x 1024 -> 160 half2/lane ----
    const float4* Whh0v = (const float4*)Whh0;
    const float4* Wih1v = (const float4*)Wih12;
    const float4* Whh1v = (const float4*)Whh12;
    const float4* Wih2v = (const float4*)(Wih12 + 4 * HSZ * HSZ);
    const float4* Whh2v = (const float4*)(Whh12 + 4 * HSZ * HSZ);

    half2v w0h[4][8], wi1h[4][8], wh1h[4][8], wi2h[4][8], wh2h[4][8];
#pragma unroll
    for (int g = 0; g < 4; ++g) {
        const size_t r = (size_t)(g * HSZ + u) * HV + lane;
#pragma unroll
        for (int i = 0; i < 4; ++i) {
            float4 t;
            t = Whh0v[r + 64 * i];  w0h[g][2*i] = cvt2(t.x,t.y);  w0h[g][2*i+1] = cvt2(t.z,t.w);
            t = Wih1v[r + 64 * i];  wi1h[g][2*i] = cvt2(t.x,t.y); wi1h[g][2*i+1] = cvt2(t.z,t.w);
            t = Whh1v[r + 64 * i];  wh1h[g][2*i] = cvt2(t.x,t.y); wh1h[g][2*i+1] = cvt2(t.z,t.w);
            t = Wih2v[r + 64 * i];  wi2h[g][2*i] = cvt2(t.x,t.y); wi2h[g][2*i+1] = cvt2(t.z,t.w);
            t = Whh2v[r + 64 * i];  wh2h[g][2*i] = cvt2(t.x,t.y); wh2h[g][2*i+1] = cvt2(t.z,t.w);
        }
    }
#pragma unroll
    for (int g = 0; g < 4; ++g)
#pragma unroll
        for (int j = 0; j < 8; ++j) {
            PINH(w0h[g][j]); PINH(wi1h[g][j]); PINH(wh1h[g][j]);
            PINH(wi2h[g][j]); PINH(wh2h[g][j]);
        }

    // head weights as f16 (used only by wave u==0)
    half2v wresh[8];
    {
        const float4* wr = (const float4*)Wres;
#pragma unroll
        for (int i = 0; i < 4; ++i) {
            float4 t = wr[lane + 64 * i];
            wresh[2*i] = cvt2(t.x, t.y); wresh[2*i+1] = cvt2(t.z, t.w);
        }
    }
    const float bres0 = bres[0];

    // Drain init stores so no late init write can clobber a live tagged word.
    asm volatile("s_waitcnt vmcnt(0)" ::: "memory");
    __syncthreads();

    const unsigned long long* Tmyq =
        (const unsigned long long*)(wsb + (blockIdx.x % nrep) * REP_BYTES);

    float c0 = 0.0f, c1 = 0.0f, c2 = 0.0f;
    union Q { unsigned long long q; half2v h[2]; };

    // Wavefront pipeline, split-phase polls:
    //   iter k: [pq0 prefetched last iter] check0 -> issue pq1 -> L0 -> pub h0
    //           -> check1 -> issue pq2 -> L1 -> pub h1
    //           -> check2 -> issue pq0(next parity) -> head,L2 -> pub h2
    PollQ pq0 = poll_issue(Tmyq + 1536, tid);  // k=0 reads parity 1, array 0

    for (int k = 0; k <= TSTEPS + 2; ++k) {
        const int wp = k & 1, rp = wp ^ 1;
        const unsigned e = (unsigned)k;
        const unsigned long long* Trp = Tmyq + rp * 1536;
        const unsigned long long* Tnx = Tmyq + wp * 1536;  // next iter's read parity
        const bool pub = (k <= TSTEPS + 1);
        const unsigned tg = (unsigned)(k + 1) << 16;

        // ================= layer 0 =================
        poll_complete(pq0, Trp, e, tid, (unsigned*)lds_h[0]);
        PollQ pq1 = poll_issue(Trp + 512, tid);  // in flight during L0
        __syncthreads();

        half2v haf[8];
#pragma unroll
        for (int i = 0; i < 4; ++i) {
            Q q; q.q = lds_h[0][lane + 64 * i];
            haf[2*i] = q.h[0]; haf[2*i+1] = q.h[1];
        }

        float h0v = 0.0f;
        if (k < TSTEPS) {
            const float x0 = x[2 * k], x1 = x[2 * k + 1];
            float acc[4];
#pragma unroll
            for (int g = 0; g < 4; ++g) {
                float a = 0.0f;
#pragma unroll
                for (int j = 0; j < 8; ++j) a = FDOT2(w0h[g][j], haf[j], a);
                acc[g] = a;
            }
#pragma unroll
            for (int g = 0; g < 4; ++g)
                acc[g] = wave_reduce(acc[g]) + b0[g] + wx0a[g] * x0 + wx0b[g] * x1;
            const float ig = sigm(acc[0]), fg = sigm(acc[1]);
            const float gg = tanhf(acc[2]), og = sigm(acc[3]);
            c0 = fg * c0 + ig * gg;
            h0v = og * tanhf(c0);
        }
        if (lane == 0 && pub) {
            const unsigned wb = tg | f16bits(h0v);
            for (int rep = 0; rep < nrep; ++rep)
                st_coh32((unsigned*)(wsb + rep * REP_BYTES) + wp * 3072 + u, wb);
        }

        // ================= layer 1 =================
        poll_complete(pq1, Trp + 512, e, tid, (unsigned*)lds_h[1]);
        PollQ pq2 = poll_issue(Trp + 1024, tid);  // in flight during L1
        __syncthreads();

        half2v hbf[8];
#pragma unroll
        for (int i = 0; i < 4; ++i) {
            Q q; q.q = lds_h[1][lane + 64 * i];
            hbf[2*i] = q.h[0]; hbf[2*i+1] = q.h[1];
        }

        float h1v = 0.0f;
        if (k >= 1 && k <= TSTEPS) {
            float acc[4];
#pragma unroll
            for (int g = 0; g < 4; ++g) {
                float a = 0.0f;
#pragma unroll
                for (int j = 0; j < 8; ++j) {
                    a = FDOT2(wi1h[g][j], haf[j], a);
                    a = FDOT2(wh1h[g][j], hbf[j], a);
                }
                acc[g] = a;
            }
#pragma unroll
            for (int g = 0; g < 4; ++g) acc[g] = wave_reduce(acc[g]) + b1[g];
            const float ig = sigm(acc[0]), fg = sigm(acc[1]);
            const float gg = tanhf(acc[2]), og = sigm(acc[3]);
            c1 = fg * c1 + ig * gg;
            h1v = og * tanhf(c1);
        }
        if (lane == 0 && pub) {
            const unsigned wb = tg | f16bits(h1v);
            for (int rep = 0; rep < nrep; ++rep)
                st_coh32((unsigned*)(wsb + rep * REP_BYTES) + wp * 3072 + 1024 + u, wb);
        }

        // ================= layer 2 + head =================
        poll_complete(pq2, Trp + 1024, e, tid, (unsigned*)lds_h[2]);
        pq0 = poll_issue(Tnx, tid);  // next iter's array 0, in flight during L2
        __syncthreads();

        half2v hcf[8];
#pragma unroll
        for (int i = 0; i < 4; ++i) {
            Q q; q.q = lds_h[2][lane + 64 * i];
            hcf[2*i] = q.h[0]; hcf[2*i+1] = q.h[1];
        }

        if (u == 0 && k >= 3) {
            float a = 0.0f;
#pragma unroll
            for (int j = 0; j < 8; ++j) a = FDOT2(wresh[j], hcf[j], a);
            a = wave_reduce(a) + bres0;
            if (lane == 0) out[k - 3] = sigm(a);
        }

        float h2v = 0.0f;
        if (k >= 2 && k <= TSTEPS + 1) {
            float acc[4];
#pragma unroll
            for (int g = 0; g < 4; ++g) {
                float a = 0.0f;
#pragma unroll
                for (int j = 0; j < 8; ++j) {
                    a = FDOT2(wi2h[g][j], hbf[j], a);
                    a = FDOT2(wh2h[g][j], hcf[j], a);
                }
                acc[g] = a;
            }
#pragma unroll
            for (int g = 0; g < 4; ++g) acc[g] = wave_reduce(acc[g]) + b2[g];
            const float ig = sigm(acc[0]), fg = sigm(acc[1]);
            const float gg = tanhf(acc[2]), og = sigm(acc[3]);
            c2 = fg * c2 + ig * gg;
            h2v = og * tanhf(c2);
        }
        if (lane == 0 && pub) {
            const unsigned wb = tg | f16bits(h2v);
            for (int rep = 0; rep < nrep; ++rep)
                st_coh32((unsigned*)(wsb + rep * REP_BYTES) + wp * 3072 + 2048 + u, wb);
        }
    }
}

extern "C" void kernel_launch(void* const* d_in, const int* in_sizes, int n_in,
                              void* d_out, int out_size, void* d_ws, size_t ws_size,
                              hipStream_t stream) {
    const float* x     = (const float*)d_in[0];
    const float* Wih0  = (const float*)d_in[1];
    const float* Whh0  = (const float*)d_in[2];
    const float* bih0  = (const float*)d_in[3];
    const float* bhh0  = (const float*)d_in[4];
    const float* Wih12 = (const float*)d_in[5];
    const float* Whh12 = (const float*)d_in[6];
    const float* bih12 = (const float*)d_in[7];
    const float* bhh12 = (const float*)d_in[8];
    const float* Wres  = (const float*)d_in[9];
    const float* bres  = (const float*)d_in[10];
    float* out = (float*)d_out;
    float* ws  = (float*)d_ws;

    int nrep = (int)(ws_size / REP_BYTES);
    if (nrep > 8) nrep = 8;
    if (nrep < 1) nrep = 1;

    lstm_persist<<<dim3(NBLK), dim3(NTHR), 0, stream>>>(
        x, Wih0, Whh0, bih0, bhh0, Wih12, Whh12, bih12, bhh12,
        Wres, bres, out, ws, nrep);
}